// Round 4
// baseline (629.717 us; speedup 1.0000x reference)
//
#include <hip/hip_runtime.h>

#define NB 16
#define DMODEL 4096
#define NH 32
#define NKV 8
#define HD 128
#define SEQ 4096
#define PASTN 4095
#define EQKV 6144           // 4096 q + 1024 k + 1024 v rows
#define NCHUNK 8
#define CHUNKS 512
#define PSTRIDE 136         // partials stride (16B aligned)
#define SCALE 0.08838834764831845f  // 1/sqrt(128)

typedef float v4f __attribute__((ext_vector_type(4)));

// ---------------- Kernel 1: QKV projection, K-split x4 ---------------------
// grid (EQKV/16, 4); block 256 = 4 waves x 4 rows; each block does a K-quarter.
__global__ __launch_bounds__(256) void qkv_proj(
    const float* __restrict__ hs, const float* __restrict__ Wq,
    const float* __restrict__ Wk, const float* __restrict__ Wv,
    float* __restrict__ raw4 /* [4][B][EQKV] */) {
  __shared__ __align__(16) float smem[4 * 32 * 65];
  const int tid = threadIdx.x, wid = tid >> 6, lane = tid & 63;
  const int e0 = blockIdx.x * 16 + wid * 4;
  const int ks = blockIdx.y;
  const int kbase = ks * 1024;

  const float* wrow[4];
#pragma unroll
  for (int r = 0; r < 4; ++r) {
    int e = e0 + r;
    wrow[r] = (e < 4096) ? (Wq + (size_t)e * DMODEL)
            : (e < 5120) ? (Wk + (size_t)(e - 4096) * DMODEL)
                         : (Wv + (size_t)(e - 5120) * DMODEL);
  }

  float acc[4][16];
#pragma unroll
  for (int r = 0; r < 4; ++r)
#pragma unroll
    for (int b = 0; b < 16; ++b) acc[r][b] = 0.f;

  float* ld = smem;  // [16][256]
  for (int kc0 = 0; kc0 < 4; ++kc0) {
    const int k0 = kbase + kc0 * 256;
    __syncthreads();
#pragma unroll
    for (int i = 0; i < 4; ++i) {
      int flat = i * 1024 + tid * 4;
      int bb = flat >> 8, c = flat & 255;
      *(v4f*)(&ld[bb * 256 + c]) = *(const v4f*)(hs + (size_t)bb * DMODEL + k0 + c);
    }
    __syncthreads();
    v4f w4[4];
#pragma unroll
    for (int r = 0; r < 4; ++r) w4[r] = *(const v4f*)(wrow[r] + k0 + lane * 4);
#pragma unroll
    for (int b = 0; b < 16; ++b) {
      v4f h4 = *(const v4f*)(&ld[b * 256 + lane * 4]);
#pragma unroll
      for (int r = 0; r < 4; ++r) {
        v4f t = w4[r] * h4;
        acc[r][b] += t[0] + t[1] + t[2] + t[3];
      }
    }
  }

#pragma unroll
  for (int r = 0; r < 4; ++r)
#pragma unroll
    for (int b = 0; b < 16; ++b) acc[r][b] += __shfl_xor(acc[r][b], 32);

  __syncthreads();
  if (lane < 32) {
#pragma unroll
    for (int r = 0; r < 4; ++r)
#pragma unroll
      for (int b = 0; b < 16; ++b)
        smem[(wid * 32 + lane) * 65 + r * 16 + b] = acc[r][b];
  }
  __syncthreads();
  float s = 0.f;
#pragma unroll
  for (int t2 = 0; t2 < 32; ++t2) s += smem[(wid * 32 + t2) * 65 + lane];
  const int r = lane >> 4, bb = lane & 15;
  raw4[((size_t)ks * NB + bb) * EQKV + e0 + r] = s;
}

// ---------------- Kernel 2: sum K-partials + RoPE + scatter ----------------
__global__ void rope_scatter(const float* __restrict__ raw4,
                             const void* __restrict__ pos_ids,
                             float* __restrict__ qout,
                             float* __restrict__ kc, float* __restrict__ vc) {
  __shared__ float row[128];
  const int b = blockIdx.y, j = blockIdx.x, d = threadIdx.x;  // 128 threads
  const int e = (j < 32) ? j * 128 + d
              : (j < 40) ? 4096 + (j - 32) * 128 + d
                         : 5120 + (j - 40) * 128 + d;
  float sum = 0.f;
#pragma unroll
  for (int ks = 0; ks < 4; ++ks)
    sum += raw4[((size_t)ks * NB + b) * EQKV + e];
  row[d] = sum;
  __syncthreads();

  const int* pi = (const int*)pos_ids;
  long long pos = (pi[1] == 0 && pi[0] != 0) ? ((const long long*)pos_ids)[b]
                                             : (long long)pi[b];
  const float fpos = (float)pos;

  if (j < 40) {
    int i = d & 63;
    float inv_freq = powf(10000.f, -(float)(2 * i) * (1.f / 128.f));
    float ang = fpos * inv_freq;
    float sn, cs;
    sincosf(ang, &sn, &cs);
    float x = row[d];
    float rot = (d < 64) ? -row[d + 64] : row[d - 64];
    float val = x * cs + rot * sn;
    if (j < 32) {
      qout[(size_t)b * (NH * HD) + j * HD + d] = val;
    } else {
      int kvh = j - 32;
      kc[(((size_t)b * NKV + kvh) * SEQ + PASTN) * HD + d] = val;
    }
  } else {
    int kvh = j - 40;
    vc[(((size_t)b * NKV + kvh) * SEQ + PASTN) * HD + d] = row[d];
  }
}

// ---------------- Kernel 3: barrier-free fused copy + flash-decode --------
// grid (chunk=8, kv=8, b=16); 4 waves/block, wave owns 128 rows (all 4 heads).
// lane = r*16 + g: row s0+r, dim octet g. Zero load redundancy.
__global__ __launch_bounds__(256, 4) void attn_decode(
    const float* __restrict__ pastK, const float* __restrict__ pastV,
    const float* __restrict__ qv, const float* __restrict__ mask,
    float* __restrict__ kc, float* __restrict__ vc,
    float* __restrict__ part /* [B][32][NCHUNK][PSTRIDE] */) {
  __shared__ __align__(16) float sm[4][4][132];  // [wave][head][m,l,pad,ctx128]

  const int chunk = blockIdx.x, kv = blockIdx.y, b = blockIdx.z;
  const int tid = threadIdx.x, wid = tid >> 6, lane = tid & 63;
  const int r = lane >> 4, g = lane & 15;

  // q: all 4 heads of this kv group, octet g
  v4f q0[4], q1[4];
  const float* qb = qv + (size_t)b * (NH * HD) + kv * 4 * HD + g * 8;
#pragma unroll
  for (int h = 0; h < 4; ++h) {
    q0[h] = *(const v4f*)(qb + h * HD);
    q1[h] = *(const v4f*)(qb + h * HD + 4);
  }

  const size_t prow = ((size_t)b * NKV + kv) * PASTN;
  const size_t crow = ((size_t)b * NKV + kv) * SEQ;
  const int base = chunk * CHUNKS + wid * 128;
  const float* mrow = mask + (size_t)b * SEQ;

  float m[4], l[4];
  v4f c0[4], c1[4];
#pragma unroll
  for (int h = 0; h < 4; ++h) {
    m[h] = -1e30f; l[h] = 0.f;
    c0[h] = (v4f){0.f, 0.f, 0.f, 0.f};
    c1[h] = (v4f){0.f, 0.f, 0.f, 0.f};
  }

  for (int t = 0; t < 32; ++t) {
    const int s0 = base + t * 4;
    const int s = s0 + r;
    v4f k0, k1, v0, v1;
    if (s0 + 3 < PASTN) {  // uniform fast path (all but one group chip-wide)
      const float* kp = pastK + (prow + s) * HD + g * 8;
      const float* vp = pastV + (prow + s) * HD + g * 8;
      k0 = __builtin_nontemporal_load((const v4f*)kp);
      k1 = __builtin_nontemporal_load((const v4f*)(kp + 4));
      v0 = __builtin_nontemporal_load((const v4f*)vp);
      v1 = __builtin_nontemporal_load((const v4f*)(vp + 4));
      float* kd = kc + (crow + s) * HD + g * 8;
      float* vd = vc + (crow + s) * HD + g * 8;
      __builtin_nontemporal_store(k0, (v4f*)kd);
      __builtin_nontemporal_store(k1, (v4f*)(kd + 4));
      __builtin_nontemporal_store(v0, (v4f*)vd);
      __builtin_nontemporal_store(v1, (v4f*)(vd + 4));
    } else {               // slow path: contains row 4095 (from cache)
      const float* kp = (s < PASTN) ? pastK + (prow + s) * HD + g * 8
                                    : kc + (crow + s) * HD + g * 8;
      const float* vp = (s < PASTN) ? pastV + (prow + s) * HD + g * 8
                                    : vc + (crow + s) * HD + g * 8;
      k0 = *(const v4f*)kp; k1 = *(const v4f*)(kp + 4);
      v0 = *(const v4f*)vp; v1 = *(const v4f*)(vp + 4);
      if (s < PASTN) {
        float* kd = kc + (crow + s) * HD + g * 8;
        float* vd = vc + (crow + s) * HD + g * 8;
        *(v4f*)kd = k0; *(v4f*)(kd + 4) = k1;
        *(v4f*)vd = v0; *(v4f*)(vd + 4) = v1;
      }
    }

    const float mval = mrow[s];
    float sc[4];
#pragma unroll
    for (int h = 0; h < 4; ++h) {
      v4f tv = q0[h] * k0 + q1[h] * k1;
      float d = tv[0] + tv[1] + tv[2] + tv[3];
      d += __shfl_xor(d, 1);
      d += __shfl_xor(d, 2);
      d += __shfl_xor(d, 4);
      d += __shfl_xor(d, 8);
      sc[h] = d * SCALE + mval;   // per-lane: dot for (row r, head h)
    }
#pragma unroll
    for (int h = 0; h < 4; ++h) {
      float gm = sc[h];
      gm = fmaxf(gm, __shfl_xor(gm, 16));
      gm = fmaxf(gm, __shfl_xor(gm, 32));   // max over the 4 rows -> uniform
      float mn = fmaxf(m[h], gm);
      float alpha = __expf(m[h] - mn);
      m[h] = mn;
      l[h] *= alpha;
      c0[h] *= alpha;
      c1[h] *= alpha;
      float p = __expf(sc[h] - mn);
      l[h] += p;
      c0[h] += p * v0;
      c1[h] += p * v1;
    }
  }

  // reduce l and ctx over the 4 row-groups (lane bits 4,5)
#pragma unroll
  for (int h = 0; h < 4; ++h) {
    l[h] += __shfl_xor(l[h], 16);
    l[h] += __shfl_xor(l[h], 32);
#pragma unroll
    for (int j = 0; j < 4; ++j) {
      c0[h][j] += __shfl_xor(c0[h][j], 16);
      c0[h][j] += __shfl_xor(c0[h][j], 32);
      c1[h][j] += __shfl_xor(c1[h][j], 16);
      c1[h][j] += __shfl_xor(c1[h][j], 32);
    }
  }

  if (r == 0) {
#pragma unroll
    for (int h = 0; h < 4; ++h) {
      if (g == 0) { sm[wid][h][0] = m[h]; sm[wid][h][1] = l[h]; }
      *(v4f*)(&sm[wid][h][4 + g * 8]) = c0[h];
      *(v4f*)(&sm[wid][h][8 + g * 8]) = c1[h];
    }
  }
  __syncthreads();

  // wave `wid` merges head `wid` across the 4 wave-slices
  float mstar = -1e30f;
#pragma unroll
  for (int sl = 0; sl < 4; ++sl) mstar = fmaxf(mstar, sm[sl][wid][0]);
  float den = 0.f;
  const int d2 = lane * 2;
  float nx = 0.f, ny = 0.f;
#pragma unroll
  for (int sl = 0; sl < 4; ++sl) {
    float w = __expf(sm[sl][wid][0] - mstar);
    den += w * sm[sl][wid][1];
    nx += w * sm[sl][wid][4 + d2];
    ny += w * sm[sl][wid][4 + d2 + 1];
  }
  float* pp = part + (((size_t)b * NH + kv * 4 + wid) * NCHUNK + chunk) * PSTRIDE;
  if (lane == 0) { pp[0] = mstar; pp[1] = den; }
  float2 nv = {nx, ny};
  *(float2*)(pp + 4 + d2) = nv;
}

// ---------------- Kernel 4: combine chunk partials ------------------------
__global__ void combine(const float* __restrict__ part, float* __restrict__ ctx) {
  const int bh = blockIdx.x;        // 0..511
  const int lane = threadIdx.x;     // 64
  const float* pp = part + (size_t)bh * NCHUNK * PSTRIDE;
  float mstar = -1e30f;
#pragma unroll
  for (int c = 0; c < NCHUNK; ++c) mstar = fmaxf(mstar, pp[c * PSTRIDE]);
  float den = 0.f, nx = 0.f, ny = 0.f;
  const int d2 = lane * 2;
#pragma unroll
  for (int c = 0; c < NCHUNK; ++c) {
    float w = __expf(pp[c * PSTRIDE] - mstar);
    den += w * pp[c * PSTRIDE + 1];
    float2 pv = *(const float2*)(pp + c * PSTRIDE + 4 + d2);
    nx += w * pv.x;
    ny += w * pv.y;
  }
  float inv = 1.0f / den;
  ctx[(size_t)bh * HD + d2] = nx * inv;
  ctx[(size_t)bh * HD + d2 + 1] = ny * inv;
}

// ---------------- Kernel 5: output projection, K-split x4 ------------------
__global__ __launch_bounds__(256) void out_proj(
    const float* __restrict__ ctx, const float* __restrict__ Wo,
    float* __restrict__ out4 /* [4][B][DMODEL] */) {
  __shared__ __align__(16) float smem[4 * 32 * 65];
  const int tid = threadIdx.x, wid = tid >> 6, lane = tid & 63;
  const int e0 = blockIdx.x * 16 + wid * 4;
  const int ks = blockIdx.y;
  const int kbase = ks * 1024;

  float acc[4][16];
#pragma unroll
  for (int r = 0; r < 4; ++r)
#pragma unroll
    for (int b = 0; b < 16; ++b) acc[r][b] = 0.f;

  float* ld = smem;  // [16][256]
  for (int kc0 = 0; kc0 < 4; ++kc0) {
    const int k0 = kbase + kc0 * 256;
    __syncthreads();
#pragma unroll
    for (int i = 0; i < 4; ++i) {
      int flat = i * 1024 + tid * 4;
      int bb = flat >> 8, c = flat & 255;
      *(v4f*)(&ld[bb * 256 + c]) = *(const v4f*)(ctx + (size_t)bb * DMODEL + k0 + c);
    }
    __syncthreads();
    v4f w4[4];
#pragma unroll
    for (int r = 0; r < 4; ++r)
      w4[r] = *(const v4f*)(Wo + (size_t)(e0 + r) * DMODEL + k0 + lane * 4);
#pragma unroll
    for (int b = 0; b < 16; ++b) {
      v4f h4 = *(const v4f*)(&ld[b * 256 + lane * 4]);
#pragma unroll
      for (int r = 0; r < 4; ++r) {
        v4f t = w4[r] * h4;
        acc[r][b] += t[0] + t[1] + t[2] + t[3];
      }
    }
  }

#pragma unroll
  for (int r = 0; r < 4; ++r)
#pragma unroll
    for (int b = 0; b < 16; ++b) acc[r][b] += __shfl_xor(acc[r][b], 32);

  __syncthreads();
  if (lane < 32) {
#pragma unroll
    for (int r = 0; r < 4; ++r)
#pragma unroll
      for (int b = 0; b < 16; ++b)
        smem[(wid * 32 + lane) * 65 + r * 16 + b] = acc[r][b];
  }
  __syncthreads();
  float s = 0.f;
#pragma unroll
  for (int t2 = 0; t2 < 32; ++t2) s += smem[(wid * 32 + t2) * 65 + lane];
  const int r = lane >> 4, bb = lane & 15;
  out4[((size_t)ks * NB + bb) * DMODEL + e0 + r] = s;
}

// ---------------- Kernel 6: sum out_proj K-partials ------------------------
__global__ void combine4(const float* __restrict__ p4, float* __restrict__ out) {
  const int i = blockIdx.x * 256 + threadIdx.x;  // 65536 total
  out[i] = p4[i] + p4[(size_t)NB * DMODEL + i] +
           p4[2 * (size_t)NB * DMODEL + i] + p4[3 * (size_t)NB * DMODEL + i];
}

// ---------------------------------------------------------------------------
extern "C" void kernel_launch(void* const* d_in, const int* in_sizes, int n_in,
                              void* d_out, int out_size, void* d_ws, size_t ws_size,
                              hipStream_t stream) {
  const float* hs    = (const float*)d_in[0];
  const float* mask  = (const float*)d_in[1];
  const void*  pos   = d_in[2];
  const float* pastK = (const float*)d_in[3];
  const float* pastV = (const float*)d_in[4];
  const float* Wq    = (const float*)d_in[5];
  const float* Wk    = (const float*)d_in[6];
  const float* Wv    = (const float*)d_in[7];
  const float* Wo    = (const float*)d_in[8];

  float* out  = (float*)d_out;
  float* attn = out;                                        // 16*4096
  float* kc   = out + (size_t)NB * DMODEL;                  // 16*8*4096*128
  float* vc   = kc + (size_t)NB * NKV * SEQ * HD;

  float* ws      = (float*)d_ws;
  float* ws_q    = ws;                                         // 65536
  float* ws_raw4 = ws_q + (size_t)NB * NH * HD;                // 4*16*6144
  float* ws_part = ws_raw4 + 4 * (size_t)NB * EQKV;            // 16*32*8*136
  float* ws_ctx  = ws_part + (size_t)NB * NH * NCHUNK * PSTRIDE; // 65536
  float* ws_out4 = ws_ctx + (size_t)NB * NH * HD;              // 4*16*4096

  qkv_proj<<<dim3(EQKV / 16, 4), 256, 0, stream>>>(hs, Wq, Wk, Wv, ws_raw4);
  rope_scatter<<<dim3(48, NB), 128, 0, stream>>>(ws_raw4, pos, ws_q, kc, vc);
  attn_decode<<<dim3(NCHUNK, NKV, NB), 256, 0, stream>>>(pastK, pastV, ws_q, mask,
                                                         kc, vc, ws_part);
  combine<<<NB * NH, 64, 0, stream>>>(ws_part, ws_ctx);
  out_proj<<<dim3(DMODEL / 16, 4), 256, 0, stream>>>(ws_ctx, Wo, ws_out4);
  combine4<<<NB * DMODEL / 256, 256, 0, stream>>>(ws_out4, attn);
}

// Round 5
// 583.705 us; speedup vs baseline: 1.0788x; 1.0788x over previous
//
#include <hip/hip_runtime.h>

#define NB 16
#define DMODEL 4096
#define NH 32
#define NKV 8
#define HD 128
#define SEQ 4096
#define PASTN 4095
#define EQKV 6144           // 4096 q + 1024 k + 1024 v rows
#define NCHUNK 8
#define CHUNKS 512
#define PSTRIDE 136         // partials stride (16B aligned)
#define SCALE 0.08838834764831845f  // 1/sqrt(128)

typedef float v4f __attribute__((ext_vector_type(4)));

// ---------------- Kernel 1: QKV projection, K-split x4 ---------------------
// grid (EQKV/16, 4); block 256 = 4 waves x 4 rows; each block does a K-quarter.
__global__ __launch_bounds__(256) void qkv_proj(
    const float* __restrict__ hs, const float* __restrict__ Wq,
    const float* __restrict__ Wk, const float* __restrict__ Wv,
    float* __restrict__ raw4 /* [4][B][EQKV] */) {
  __shared__ __align__(16) float smem[4 * 32 * 65];
  const int tid = threadIdx.x, wid = tid >> 6, lane = tid & 63;
  const int e0 = blockIdx.x * 16 + wid * 4;
  const int ks = blockIdx.y;
  const int kbase = ks * 1024;

  const float* wrow[4];
#pragma unroll
  for (int r = 0; r < 4; ++r) {
    int e = e0 + r;
    wrow[r] = (e < 4096) ? (Wq + (size_t)e * DMODEL)
            : (e < 5120) ? (Wk + (size_t)(e - 4096) * DMODEL)
                         : (Wv + (size_t)(e - 5120) * DMODEL);
  }

  float acc[4][16];
#pragma unroll
  for (int r = 0; r < 4; ++r)
#pragma unroll
    for (int b = 0; b < 16; ++b) acc[r][b] = 0.f;

  float* ld = smem;  // [16][256]
  for (int kc0 = 0; kc0 < 4; ++kc0) {
    const int k0 = kbase + kc0 * 256;
    __syncthreads();
#pragma unroll
    for (int i = 0; i < 4; ++i) {
      int flat = i * 1024 + tid * 4;
      int bb = flat >> 8, c = flat & 255;
      *(v4f*)(&ld[bb * 256 + c]) = *(const v4f*)(hs + (size_t)bb * DMODEL + k0 + c);
    }
    __syncthreads();
    v4f w4[4];
#pragma unroll
    for (int r = 0; r < 4; ++r) w4[r] = *(const v4f*)(wrow[r] + k0 + lane * 4);
#pragma unroll
    for (int b = 0; b < 16; ++b) {
      v4f h4 = *(const v4f*)(&ld[b * 256 + lane * 4]);
#pragma unroll
      for (int r = 0; r < 4; ++r) {
        v4f t = w4[r] * h4;
        acc[r][b] += t[0] + t[1] + t[2] + t[3];
      }
    }
  }

#pragma unroll
  for (int r = 0; r < 4; ++r)
#pragma unroll
    for (int b = 0; b < 16; ++b) acc[r][b] += __shfl_xor(acc[r][b], 32);

  __syncthreads();
  if (lane < 32) {
#pragma unroll
    for (int r = 0; r < 4; ++r)
#pragma unroll
      for (int b = 0; b < 16; ++b)
        smem[(wid * 32 + lane) * 65 + r * 16 + b] = acc[r][b];
  }
  __syncthreads();
  float s = 0.f;
#pragma unroll
  for (int t2 = 0; t2 < 32; ++t2) s += smem[(wid * 32 + t2) * 65 + lane];
  const int r = lane >> 4, bb = lane & 15;
  raw4[((size_t)ks * NB + bb) * EQKV + e0 + r] = s;
}

// ---------------- Kernel 2: sum K-partials + RoPE + scatter ----------------
__global__ void rope_scatter(const float* __restrict__ raw4,
                             const void* __restrict__ pos_ids,
                             float* __restrict__ qout,
                             float* __restrict__ kc, float* __restrict__ vc) {
  __shared__ float row[128];
  const int b = blockIdx.y, j = blockIdx.x, d = threadIdx.x;  // 128 threads
  const int e = (j < 32) ? j * 128 + d
              : (j < 40) ? 4096 + (j - 32) * 128 + d
                         : 5120 + (j - 40) * 128 + d;
  float sum = 0.f;
#pragma unroll
  for (int ks = 0; ks < 4; ++ks)
    sum += raw4[((size_t)ks * NB + b) * EQKV + e];
  row[d] = sum;
  __syncthreads();

  const int* pi = (const int*)pos_ids;
  long long pos = (pi[1] == 0 && pi[0] != 0) ? ((const long long*)pos_ids)[b]
                                             : (long long)pi[b];
  const float fpos = (float)pos;

  if (j < 40) {
    int i = d & 63;
    float inv_freq = powf(10000.f, -(float)(2 * i) * (1.f / 128.f));
    float ang = fpos * inv_freq;
    float sn, cs;
    sincosf(ang, &sn, &cs);
    float x = row[d];
    float rot = (d < 64) ? -row[d + 64] : row[d - 64];
    float val = x * cs + rot * sn;
    if (j < 32) {
      qout[(size_t)b * (NH * HD) + j * HD + d] = val;
    } else {
      int kvh = j - 32;
      kc[(((size_t)b * NKV + kvh) * SEQ + PASTN) * HD + d] = val;
    }
  } else {
    int kvh = j - 40;
    vc[(((size_t)b * NKV + kvh) * SEQ + PASTN) * HD + d] = row[d];
  }
}

// ---------------- Kernel 3: barrier-free fused copy + flash-decode --------
// R3-winning version: lane = h*16 + g (head h, dim octet g). Wave owns 128
// rows for ALL 4 heads of its kv group. No LDS in main loop.
__global__ __launch_bounds__(256, 4) void attn_decode(
    const float* __restrict__ pastK, const float* __restrict__ pastV,
    const float* __restrict__ qv, const float* __restrict__ mask,
    float* __restrict__ kc, float* __restrict__ vc,
    float* __restrict__ part /* [B][32][NCHUNK][PSTRIDE] */) {
  __shared__ __align__(16) float sm[4][4][132];  // [wave][head][m,l,pad,ctx128]

  const int chunk = blockIdx.x, kv = blockIdx.y, b = blockIdx.z;
  const int tid = threadIdx.x, wid = tid >> 6, lane = tid & 63;
  const int h = lane >> 4, g = lane & 15;

  const float* qp = qv + (size_t)b * (NH * HD) + (kv * 4 + h) * HD + g * 8;
  const v4f q0 = *(const v4f*)qp;
  const v4f q1 = *(const v4f*)(qp + 4);

  const size_t prow = ((size_t)b * NKV + kv) * PASTN;
  const size_t crow = ((size_t)b * NKV + kv) * SEQ;
  const int base = chunk * CHUNKS + wid * 128;
  const float* mrow = mask + (size_t)b * SEQ;

  float m = -1e30f, l = 0.f;
  v4f c0 = {0.f, 0.f, 0.f, 0.f}, c1 = {0.f, 0.f, 0.f, 0.f};

  for (int t = 0; t < 32; ++t) {  // 4 rows per group
    const int s0 = base + t * 4;
    v4f k0r[4], k1r[4], v0r[4], v1r[4];
#pragma unroll
    for (int r = 0; r < 4; ++r) {
      const int s = s0 + r;
      const float *kp, *vp;
      if (s < PASTN) {
        kp = pastK + (prow + s) * HD;
        vp = pastV + (prow + s) * HD;
      } else {
        kp = kc + (crow + s) * HD;
        vp = vc + (crow + s) * HD;
      }
      k0r[r] = __builtin_nontemporal_load((const v4f*)(kp + g * 8));
      k1r[r] = __builtin_nontemporal_load((const v4f*)(kp + g * 8 + 4));
      v0r[r] = __builtin_nontemporal_load((const v4f*)(vp + g * 8));
      v1r[r] = __builtin_nontemporal_load((const v4f*)(vp + g * 8 + 4));
    }
    // write-through cache copy (h==0 lanes cover the full row)
#pragma unroll
    for (int r = 0; r < 4; ++r) {
      const int s = s0 + r;
      if (s < PASTN && h == 0) {
        float* kd = kc + (crow + s) * HD + g * 8;
        float* vd = vc + (crow + s) * HD + g * 8;
        __builtin_nontemporal_store(k0r[r], (v4f*)kd);
        __builtin_nontemporal_store(k1r[r], (v4f*)(kd + 4));
        __builtin_nontemporal_store(v0r[r], (v4f*)vd);
        __builtin_nontemporal_store(v1r[r], (v4f*)(vd + 4));
      }
    }
    // scores (reduced within each 16-lane head group)
    float sc[4];
#pragma unroll
    for (int r = 0; r < 4; ++r) {
      v4f tv = q0 * k0r[r] + q1 * k1r[r];
      float d = tv[0] + tv[1] + tv[2] + tv[3];
      d += __shfl_xor(d, 1);
      d += __shfl_xor(d, 2);
      d += __shfl_xor(d, 4);
      d += __shfl_xor(d, 8);
      sc[r] = d * SCALE + mrow[s0 + r];
    }
    // online softmax (per-lane; identical within head group)
    float gm = fmaxf(fmaxf(sc[0], sc[1]), fmaxf(sc[2], sc[3]));
    float mn = fmaxf(m, gm);
    float alpha = __expf(m - mn);
    l *= alpha;
    c0 *= alpha;
    c1 *= alpha;
    m = mn;
#pragma unroll
    for (int r = 0; r < 4; ++r) {
      float p = __expf(sc[r] - mn);
      l += p;
      c0 += p * v0r[r];
      c1 += p * v1r[r];
    }
  }

  // in-block merge of the 4 wave-slices (one barrier, end of kernel)
  if (g == 0) { sm[wid][h][0] = m; sm[wid][h][1] = l; }
  *(v4f*)(&sm[wid][h][4 + g * 8]) = c0;
  *(v4f*)(&sm[wid][h][8 + g * 8]) = c1;
  __syncthreads();

  // wave `wid` merges head `wid`
  float mstar = -1e30f;
#pragma unroll
  for (int sl = 0; sl < 4; ++sl) mstar = fmaxf(mstar, sm[sl][wid][0]);
  float den = 0.f;
  const int d2 = lane * 2;
  float nx = 0.f, ny = 0.f;
#pragma unroll
  for (int sl = 0; sl < 4; ++sl) {
    float w = __expf(sm[sl][wid][0] - mstar);
    den += w * sm[sl][wid][1];
    nx += w * sm[sl][wid][4 + d2];
    ny += w * sm[sl][wid][4 + d2 + 1];
  }
  float* pp = part + (((size_t)b * NH + kv * 4 + wid) * NCHUNK + chunk) * PSTRIDE;
  if (lane == 0) { pp[0] = mstar; pp[1] = den; }
  float2 nv = {nx, ny};
  *(float2*)(pp + 4 + d2) = nv;
}

// ---------------- Kernel 4: combine chunk partials ------------------------
__global__ void combine(const float* __restrict__ part, float* __restrict__ ctx) {
  const int bh = blockIdx.x;        // 0..511
  const int lane = threadIdx.x;     // 64
  const float* pp = part + (size_t)bh * NCHUNK * PSTRIDE;
  float mstar = -1e30f;
#pragma unroll
  for (int c = 0; c < NCHUNK; ++c) mstar = fmaxf(mstar, pp[c * PSTRIDE]);
  float den = 0.f, nx = 0.f, ny = 0.f;
  const int d2 = lane * 2;
#pragma unroll
  for (int c = 0; c < NCHUNK; ++c) {
    float w = __expf(pp[c * PSTRIDE] - mstar);
    den += w * pp[c * PSTRIDE + 1];
    float2 pv = *(const float2*)(pp + c * PSTRIDE + 4 + d2);
    nx += w * pv.x;
    ny += w * pv.y;
  }
  float inv = 1.0f / den;
  ctx[(size_t)bh * HD + d2] = nx * inv;
  ctx[(size_t)bh * HD + d2 + 1] = ny * inv;
}

// ---------------- Kernel 5: output projection, K-split x4 ------------------
__global__ __launch_bounds__(256) void out_proj(
    const float* __restrict__ ctx, const float* __restrict__ Wo,
    float* __restrict__ out4 /* [4][B][DMODEL] */) {
  __shared__ __align__(16) float smem[4 * 32 * 65];
  const int tid = threadIdx.x, wid = tid >> 6, lane = tid & 63;
  const int e0 = blockIdx.x * 16 + wid * 4;
  const int ks = blockIdx.y;
  const int kbase = ks * 1024;

  float acc[4][16];
#pragma unroll
  for (int r = 0; r < 4; ++r)
#pragma unroll
    for (int b = 0; b < 16; ++b) acc[r][b] = 0.f;

  float* ld = smem;  // [16][256]
  for (int kc0 = 0; kc0 < 4; ++kc0) {
    const int k0 = kbase + kc0 * 256;
    __syncthreads();
#pragma unroll
    for (int i = 0; i < 4; ++i) {
      int flat = i * 1024 + tid * 4;
      int bb = flat >> 8, c = flat & 255;
      *(v4f*)(&ld[bb * 256 + c]) = *(const v4f*)(ctx + (size_t)bb * DMODEL + k0 + c);
    }
    __syncthreads();
    v4f w4[4];
#pragma unroll
    for (int r = 0; r < 4; ++r)
      w4[r] = *(const v4f*)(Wo + (size_t)(e0 + r) * DMODEL + k0 + lane * 4);
#pragma unroll
    for (int b = 0; b < 16; ++b) {
      v4f h4 = *(const v4f*)(&ld[b * 256 + lane * 4]);
#pragma unroll
      for (int r = 0; r < 4; ++r) {
        v4f t = w4[r] * h4;
        acc[r][b] += t[0] + t[1] + t[2] + t[3];
      }
    }
  }

#pragma unroll
  for (int r = 0; r < 4; ++r)
#pragma unroll
    for (int b = 0; b < 16; ++b) acc[r][b] += __shfl_xor(acc[r][b], 32);

  __syncthreads();
  if (lane < 32) {
#pragma unroll
    for (int r = 0; r < 4; ++r)
#pragma unroll
      for (int b = 0; b < 16; ++b)
        smem[(wid * 32 + lane) * 65 + r * 16 + b] = acc[r][b];
  }
  __syncthreads();
  float s = 0.f;
#pragma unroll
  for (int t2 = 0; t2 < 32; ++t2) s += smem[(wid * 32 + t2) * 65 + lane];
  const int r = lane >> 4, bb = lane & 15;
  out4[((size_t)ks * NB + bb) * DMODEL + e0 + r] = s;
}

// ---------------- Kernel 6: sum out_proj K-partials ------------------------
__global__ void combine4(const float* __restrict__ p4, float* __restrict__ out) {
  const int i = blockIdx.x * 256 + threadIdx.x;  // 65536 total
  out[i] = p4[i] + p4[(size_t)NB * DMODEL + i] +
           p4[2 * (size_t)NB * DMODEL + i] + p4[3 * (size_t)NB * DMODEL + i];
}

// ---------------------------------------------------------------------------
extern "C" void kernel_launch(void* const* d_in, const int* in_sizes, int n_in,
                              void* d_out, int out_size, void* d_ws, size_t ws_size,
                              hipStream_t stream) {
  const float* hs    = (const float*)d_in[0];
  const float* mask  = (const float*)d_in[1];
  const void*  pos   = d_in[2];
  const float* pastK = (const float*)d_in[3];
  const float* pastV = (const float*)d_in[4];
  const float* Wq    = (const float*)d_in[5];
  const float* Wk    = (const float*)d_in[6];
  const float* Wv    = (const float*)d_in[7];
  const float* Wo    = (const float*)d_in[8];

  float* out  = (float*)d_out;
  float* attn = out;                                        // 16*4096
  float* kc   = out + (size_t)NB * DMODEL;                  // 16*8*4096*128
  float* vc   = kc + (size_t)NB * NKV * SEQ * HD;

  float* ws      = (float*)d_ws;
  float* ws_q    = ws;                                         // 65536
  float* ws_raw4 = ws_q + (size_t)NB * NH * HD;                // 4*16*6144
  float* ws_part = ws_raw4 + 4 * (size_t)NB * EQKV;            // 16*32*8*136
  float* ws_ctx  = ws_part + (size_t)NB * NH * NCHUNK * PSTRIDE; // 65536
  float* ws_out4 = ws_ctx + (size_t)NB * NH * HD;              // 4*16*4096

  qkv_proj<<<dim3(EQKV / 16, 4), 256, 0, stream>>>(hs, Wq, Wk, Wv, ws_raw4);
  rope_scatter<<<dim3(48, NB), 128, 0, stream>>>(ws_raw4, pos, ws_q, kc, vc);
  attn_decode<<<dim3(NCHUNK, NKV, NB), 256, 0, stream>>>(pastK, pastV, ws_q, mask,
                                                         kc, vc, ws_part);
  combine<<<NB * NH, 64, 0, stream>>>(ws_part, ws_ctx);
  out_proj<<<dim3(DMODEL / 16, 4), 256, 0, stream>>>(ws_ctx, Wo, ws_out4);
  combine4<<<NB * DMODEL / 256, 256, 0, stream>>>(ws_out4, attn);
}

// Round 6
// 327.009 us; speedup vs baseline: 1.9257x; 1.7850x over previous
//
#include <hip/hip_runtime.h>

#define NB 16
#define DMODEL 4096
#define NH 32
#define NKV 8
#define HD 128
#define SEQ 4096
#define PASTN 4095
#define EQKV 6144           // 4096 q + 1024 k + 1024 v rows
#define NCHUNK 8
#define CHUNKS 512
#define PSTRIDE 136         // partials stride (16B aligned)
#define SCALE 0.08838834764831845f  // 1/sqrt(128)

typedef float v4f __attribute__((ext_vector_type(4)));

// ---------------- Kernel 1: QKV projection (non-split, R3-winning form) ----
// grid 384; 4 waves/block, 4 rows/wave; hs chunk staged in LDS.
__global__ __launch_bounds__(256) void qkv_proj(
    const float* __restrict__ hs, const float* __restrict__ Wq,
    const float* __restrict__ Wk, const float* __restrict__ Wv,
    float* __restrict__ raw /* [B][6144] */) {
  __shared__ __align__(16) float smem[4 * 32 * 65];
  const int tid = threadIdx.x, wid = tid >> 6, lane = tid & 63;
  const int e0 = blockIdx.x * 16 + wid * 4;

  const float* wrow[4];
#pragma unroll
  for (int r = 0; r < 4; ++r) {
    int e = e0 + r;
    wrow[r] = (e < 4096) ? (Wq + (size_t)e * DMODEL)
            : (e < 5120) ? (Wk + (size_t)(e - 4096) * DMODEL)
                         : (Wv + (size_t)(e - 5120) * DMODEL);
  }

  float acc[4][16];
#pragma unroll
  for (int r = 0; r < 4; ++r)
#pragma unroll
    for (int b = 0; b < 16; ++b) acc[r][b] = 0.f;

  float* ld = smem;  // [16][256]
  for (int k0 = 0; k0 < DMODEL; k0 += 256) {
    __syncthreads();
#pragma unroll
    for (int i = 0; i < 4; ++i) {
      int flat = i * 1024 + tid * 4;
      int bb = flat >> 8, c = flat & 255;
      *(v4f*)(&ld[bb * 256 + c]) = *(const v4f*)(hs + (size_t)bb * DMODEL + k0 + c);
    }
    __syncthreads();
    v4f w4[4];
#pragma unroll
    for (int r = 0; r < 4; ++r) w4[r] = *(const v4f*)(wrow[r] + k0 + lane * 4);
#pragma unroll
    for (int b = 0; b < 16; ++b) {
      v4f h4 = *(const v4f*)(&ld[b * 256 + lane * 4]);
#pragma unroll
      for (int r = 0; r < 4; ++r) {
        v4f t = w4[r] * h4;
        acc[r][b] += t[0] + t[1] + t[2] + t[3];
      }
    }
  }

#pragma unroll
  for (int r = 0; r < 4; ++r)
#pragma unroll
    for (int b = 0; b < 16; ++b) acc[r][b] += __shfl_xor(acc[r][b], 32);

  __syncthreads();
  if (lane < 32) {
#pragma unroll
    for (int r = 0; r < 4; ++r)
#pragma unroll
      for (int b = 0; b < 16; ++b)
        smem[(wid * 32 + lane) * 65 + r * 16 + b] = acc[r][b];
  }
  __syncthreads();
  float s = 0.f;
#pragma unroll
  for (int t2 = 0; t2 < 32; ++t2) s += smem[(wid * 32 + t2) * 65 + lane];
  const int r = lane >> 4, bb = lane & 15;
  raw[(size_t)bb * EQKV + e0 + r] = s;
}

// ---------------- Kernel 2: RoPE + scatter new row into caches ------------
__device__ __forceinline__ float rope_val(const float* src, int d, float pos) {
  int i = d & 63;
  float inv_freq = powf(10000.f, -(float)(2 * i) * (1.f / 128.f));
  float ang = pos * inv_freq;
  float s, c;
  sincosf(ang, &s, &c);
  float x = src[d];
  float rot = (d < 64) ? -src[d + 64] : src[d - 64];
  return x * c + rot * s;
}

__global__ void rope_scatter(const float* __restrict__ raw,
                             const void* __restrict__ pos_ids,
                             float* __restrict__ qout,
                             float* __restrict__ kc, float* __restrict__ vc) {
  const int b = blockIdx.y, j = blockIdx.x, d = threadIdx.x;  // 128 threads
  const int* pi = (const int*)pos_ids;
  long long pos = (pi[1] == 0 && pi[0] != 0) ? ((const long long*)pos_ids)[b]
                                             : (long long)pi[b];
  const float fpos = (float)pos;
  if (j < 32) {
    const float* src = raw + (size_t)b * EQKV + j * HD;
    qout[(size_t)b * (NH * HD) + j * HD + d] = rope_val(src, d, fpos);
  } else if (j < 40) {
    int kvh = j - 32;
    const float* src = raw + (size_t)b * EQKV + 4096 + kvh * HD;
    kc[(((size_t)b * NKV + kvh) * SEQ + PASTN) * HD + d] = rope_val(src, d, fpos);
  } else {
    int kvh = j - 40;
    vc[(((size_t)b * NKV + kvh) * SEQ + PASTN) * HD + d] =
        raw[(size_t)b * EQKV + 5120 + kvh * HD + d];
  }
}

// ---------------- Kernel 3: barrier-free fused copy + flash-decode --------
// h-layout, CONTIGUOUS-QUARTER addressing: lane = h*16 + g holds row floats
// [4g,4g+4) and [64+4g,64+4g+4). Every load/store instruction covers a full
// contiguous 256B run (no partial-line NT stores).
__global__ __launch_bounds__(256, 4) void attn_decode(
    const float* __restrict__ pastK, const float* __restrict__ pastV,
    const float* __restrict__ qv, const float* __restrict__ mask,
    float* __restrict__ kc, float* __restrict__ vc,
    float* __restrict__ part /* [B][32][NCHUNK][PSTRIDE] */) {
  __shared__ __align__(16) float sm[4][4][132];  // [wave][head][m,l,pad,ctx128]

  const int chunk = blockIdx.x, kv = blockIdx.y, b = blockIdx.z;
  const int tid = threadIdx.x, wid = tid >> 6, lane = tid & 63;
  const int h = lane >> 4, g = lane & 15;
  const int o0 = g * 4, o1 = 64 + g * 4;   // contiguous quarter offsets

  const float* qp = qv + (size_t)b * (NH * HD) + (kv * 4 + h) * HD;
  const v4f q0 = *(const v4f*)(qp + o0);
  const v4f q1 = *(const v4f*)(qp + o1);

  const size_t prow = ((size_t)b * NKV + kv) * PASTN;
  const size_t crow = ((size_t)b * NKV + kv) * SEQ;
  const int base = chunk * CHUNKS + wid * 128;
  const float* mrow = mask + (size_t)b * SEQ;

  float m = -1e30f, l = 0.f;
  v4f c0 = {0.f, 0.f, 0.f, 0.f}, c1 = {0.f, 0.f, 0.f, 0.f};

  for (int t = 0; t < 32; ++t) {  // 4 rows per iteration
    const int s0 = base + t * 4;
    v4f k0r[4], k1r[4], v0r[4], v1r[4];
#pragma unroll
    for (int r = 0; r < 4; ++r) {
      const int s = s0 + r;
      const float *kp, *vp;
      if (s < PASTN) {
        kp = pastK + (prow + s) * HD;
        vp = pastV + (prow + s) * HD;
      } else {
        kp = kc + (crow + s) * HD;
        vp = vc + (crow + s) * HD;
      }
      k0r[r] = __builtin_nontemporal_load((const v4f*)(kp + o0));
      k1r[r] = __builtin_nontemporal_load((const v4f*)(kp + o1));
      v0r[r] = __builtin_nontemporal_load((const v4f*)(vp + o0));
      v1r[r] = __builtin_nontemporal_load((const v4f*)(vp + o1));
    }
    // write-through cache copy (h==0 group covers the full row, full-line)
#pragma unroll
    for (int r = 0; r < 4; ++r) {
      const int s = s0 + r;
      if (s < PASTN && h == 0) {
        float* kd = kc + (crow + s) * HD;
        float* vd = vc + (crow + s) * HD;
        __builtin_nontemporal_store(k0r[r], (v4f*)(kd + o0));
        __builtin_nontemporal_store(k1r[r], (v4f*)(kd + o1));
        __builtin_nontemporal_store(v0r[r], (v4f*)(vd + o0));
        __builtin_nontemporal_store(v1r[r], (v4f*)(vd + o1));
      }
    }
    // scores (reduced within each 16-lane head group)
    float sc[4];
#pragma unroll
    for (int r = 0; r < 4; ++r) {
      v4f tv = q0 * k0r[r] + q1 * k1r[r];
      float d = tv[0] + tv[1] + tv[2] + tv[3];
      d += __shfl_xor(d, 1);
      d += __shfl_xor(d, 2);
      d += __shfl_xor(d, 4);
      d += __shfl_xor(d, 8);
      sc[r] = d * SCALE + mrow[s0 + r];
    }
    // online softmax (per-lane; identical within head group)
    float gm = fmaxf(fmaxf(sc[0], sc[1]), fmaxf(sc[2], sc[3]));
    float mn = fmaxf(m, gm);
    float alpha = __expf(m - mn);
    l *= alpha;
    c0 *= alpha;
    c1 *= alpha;
    m = mn;
#pragma unroll
    for (int r = 0; r < 4; ++r) {
      float p = __expf(sc[r] - mn);
      l += p;
      c0 += p * v0r[r];
      c1 += p * v1r[r];
    }
  }

  // in-block merge of the 4 wave-slices (one barrier, end of kernel)
  if (g == 0) { sm[wid][h][0] = m; sm[wid][h][1] = l; }
  *(v4f*)(&sm[wid][h][4 + o0]) = c0;   // ctx floats [4g,4g+4)
  *(v4f*)(&sm[wid][h][4 + o1]) = c1;   // ctx floats [64+4g,..)
  __syncthreads();

  // wave `wid` merges head `wid` (ctx stored linearly at [4..132))
  float mstar = -1e30f;
#pragma unroll
  for (int sl = 0; sl < 4; ++sl) mstar = fmaxf(mstar, sm[sl][wid][0]);
  float den = 0.f;
  const int d2 = lane * 2;
  float nx = 0.f, ny = 0.f;
#pragma unroll
  for (int sl = 0; sl < 4; ++sl) {
    float w = __expf(sm[sl][wid][0] - mstar);
    den += w * sm[sl][wid][1];
    nx += w * sm[sl][wid][4 + d2];
    ny += w * sm[sl][wid][4 + d2 + 1];
  }
  float* pp = part + (((size_t)b * NH + kv * 4 + wid) * NCHUNK + chunk) * PSTRIDE;
  if (lane == 0) { pp[0] = mstar; pp[1] = den; }
  float2 nv = {nx, ny};
  *(float2*)(pp + 4 + d2) = nv;
}

// ---------------- Kernel 4: combine chunk partials ------------------------
__global__ void combine(const float* __restrict__ part, float* __restrict__ ctx) {
  const int bh = blockIdx.x;        // 0..511
  const int lane = threadIdx.x;     // 64
  const float* pp = part + (size_t)bh * NCHUNK * PSTRIDE;
  float mstar = -1e30f;
#pragma unroll
  for (int c = 0; c < NCHUNK; ++c) mstar = fmaxf(mstar, pp[c * PSTRIDE]);
  float den = 0.f, nx = 0.f, ny = 0.f;
  const int d2 = lane * 2;
#pragma unroll
  for (int c = 0; c < NCHUNK; ++c) {
    float w = __expf(pp[c * PSTRIDE] - mstar);
    den += w * pp[c * PSTRIDE + 1];
    float2 pv = *(const float2*)(pp + c * PSTRIDE + 4 + d2);
    nx += w * pv.x;
    ny += w * pv.y;
  }
  float inv = 1.0f / den;
  ctx[(size_t)bh * HD + d2] = nx * inv;
  ctx[(size_t)bh * HD + d2 + 1] = ny * inv;
}

// ---------------- Kernel 5: output projection (non-split, R3 form) --------
__global__ __launch_bounds__(256) void out_proj(
    const float* __restrict__ ctx, const float* __restrict__ Wo,
    float* __restrict__ out) {
  __shared__ __align__(16) float smem[4 * 32 * 65];
  const int tid = threadIdx.x, wid = tid >> 6, lane = tid & 63;
  const int e0 = blockIdx.x * 16 + wid * 4;

  float acc[4][16];
#pragma unroll
  for (int r = 0; r < 4; ++r)
#pragma unroll
    for (int b = 0; b < 16; ++b) acc[r][b] = 0.f;

  float* ld = smem;  // [16][256]
  for (int k0 = 0; k0 < DMODEL; k0 += 256) {
    __syncthreads();
#pragma unroll
    for (int i = 0; i < 4; ++i) {
      int flat = i * 1024 + tid * 4;
      int bb = flat >> 8, c = flat & 255;
      *(v4f*)(&ld[bb * 256 + c]) = *(const v4f*)(ctx + (size_t)bb * DMODEL + k0 + c);
    }
    __syncthreads();
    v4f w4[4];
#pragma unroll
    for (int r = 0; r < 4; ++r)
      w4[r] = *(const v4f*)(Wo + (size_t)(e0 + r) * DMODEL + k0 + lane * 4);
#pragma unroll
    for (int b = 0; b < 16; ++b) {
      v4f h4 = *(const v4f*)(&ld[b * 256 + lane * 4]);
#pragma unroll
      for (int r = 0; r < 4; ++r) {
        v4f t = w4[r] * h4;
        acc[r][b] += t[0] + t[1] + t[2] + t[3];
      }
    }
  }

#pragma unroll
  for (int r = 0; r < 4; ++r)
#pragma unroll
    for (int b = 0; b < 16; ++b) acc[r][b] += __shfl_xor(acc[r][b], 32);

  __syncthreads();
  if (lane < 32) {
#pragma unroll
    for (int r = 0; r < 4; ++r)
#pragma unroll
      for (int b = 0; b < 16; ++b)
        smem[(wid * 32 + lane) * 65 + r * 16 + b] = acc[r][b];
  }
  __syncthreads();
  float s = 0.f;
#pragma unroll
  for (int t2 = 0; t2 < 32; ++t2) s += smem[(wid * 32 + t2) * 65 + lane];
  const int r = lane >> 4, bb = lane & 15;
  out[(size_t)bb * DMODEL + e0 + r] = s;
}

// ---------------------------------------------------------------------------
extern "C" void kernel_launch(void* const* d_in, const int* in_sizes, int n_in,
                              void* d_out, int out_size, void* d_ws, size_t ws_size,
                              hipStream_t stream) {
  const float* hs    = (const float*)d_in[0];
  const float* mask  = (const float*)d_in[1];
  const void*  pos   = d_in[2];
  const float* pastK = (const float*)d_in[3];
  const float* pastV = (const float*)d_in[4];
  const float* Wq    = (const float*)d_in[5];
  const float* Wk    = (const float*)d_in[6];
  const float* Wv    = (const float*)d_in[7];
  const float* Wo    = (const float*)d_in[8];

  float* out  = (float*)d_out;
  float* attn = out;                                        // 16*4096
  float* kc   = out + (size_t)NB * DMODEL;                  // 16*8*4096*128
  float* vc   = kc + (size_t)NB * NKV * SEQ * HD;

  float* ws      = (float*)d_ws;
  float* ws_q    = ws;                                         // 65536
  float* ws_raw  = ws_q + (size_t)NB * NH * HD;                // 16*6144
  float* ws_part = ws_raw + (size_t)NB * EQKV;                 // 16*32*8*136
  float* ws_ctx  = ws_part + (size_t)NB * NH * NCHUNK * PSTRIDE; // 65536

  qkv_proj<<<EQKV / 16, 256, 0, stream>>>(hs, Wq, Wk, Wv, ws_raw);
  rope_scatter<<<dim3(48, NB), 128, 0, stream>>>(ws_raw, pos, ws_q, kc, vc);
  attn_decode<<<dim3(NCHUNK, NKV, NB), 256, 0, stream>>>(pastK, pastV, ws_q, mask,
                                                         kc, vc, ws_part);
  combine<<<NB * NH, 64, 0, stream>>>(ws_part, ws_ctx);
  out_proj<<<DMODEL / 16, 256, 0, stream>>>(ws_ctx, Wo, attn);
}

// Round 7
// 319.063 us; speedup vs baseline: 1.9736x; 1.0249x over previous
//
#include <hip/hip_runtime.h>

#define NB 16
#define DMODEL 4096
#define NH 32
#define NKV 8
#define HD 128
#define SEQ 4096
#define PASTN 4095
#define EQKV 6144           // 4096 q + 1024 k + 1024 v rows
#define NCHUNK 16
#define CHUNKS 256          // rows per chunk-block (SEQ/NCHUNK)
#define PSTRIDE 136         // partials stride (16B aligned)
#define SCALE 0.08838834764831845f  // 1/sqrt(128)

typedef float v4f __attribute__((ext_vector_type(4)));

// ---------------- Kernel 1: QKV projection (R6 form, unchanged) -----------
__global__ __launch_bounds__(256) void qkv_proj(
    const float* __restrict__ hs, const float* __restrict__ Wq,
    const float* __restrict__ Wk, const float* __restrict__ Wv,
    float* __restrict__ raw /* [B][6144] */) {
  __shared__ __align__(16) float smem[4 * 32 * 65];
  const int tid = threadIdx.x, wid = tid >> 6, lane = tid & 63;
  const int e0 = blockIdx.x * 16 + wid * 4;

  const float* wrow[4];
#pragma unroll
  for (int r = 0; r < 4; ++r) {
    int e = e0 + r;
    wrow[r] = (e < 4096) ? (Wq + (size_t)e * DMODEL)
            : (e < 5120) ? (Wk + (size_t)(e - 4096) * DMODEL)
                         : (Wv + (size_t)(e - 5120) * DMODEL);
  }

  float acc[4][16];
#pragma unroll
  for (int r = 0; r < 4; ++r)
#pragma unroll
    for (int b = 0; b < 16; ++b) acc[r][b] = 0.f;

  float* ld = smem;  // [16][256]
  for (int k0 = 0; k0 < DMODEL; k0 += 256) {
    __syncthreads();
#pragma unroll
    for (int i = 0; i < 4; ++i) {
      int flat = i * 1024 + tid * 4;
      int bb = flat >> 8, c = flat & 255;
      *(v4f*)(&ld[bb * 256 + c]) = *(const v4f*)(hs + (size_t)bb * DMODEL + k0 + c);
    }
    __syncthreads();
    v4f w4[4];
#pragma unroll
    for (int r = 0; r < 4; ++r) w4[r] = *(const v4f*)(wrow[r] + k0 + lane * 4);
#pragma unroll
    for (int b = 0; b < 16; ++b) {
      v4f h4 = *(const v4f*)(&ld[b * 256 + lane * 4]);
#pragma unroll
      for (int r = 0; r < 4; ++r) {
        v4f t = w4[r] * h4;
        acc[r][b] += t[0] + t[1] + t[2] + t[3];
      }
    }
  }

#pragma unroll
  for (int r = 0; r < 4; ++r)
#pragma unroll
    for (int b = 0; b < 16; ++b) acc[r][b] += __shfl_xor(acc[r][b], 32);

  __syncthreads();
  if (lane < 32) {
#pragma unroll
    for (int r = 0; r < 4; ++r)
#pragma unroll
      for (int b = 0; b < 16; ++b)
        smem[(wid * 32 + lane) * 65 + r * 16 + b] = acc[r][b];
  }
  __syncthreads();
  float s = 0.f;
#pragma unroll
  for (int t2 = 0; t2 < 32; ++t2) s += smem[(wid * 32 + t2) * 65 + lane];
  const int r = lane >> 4, bb = lane & 15;
  raw[(size_t)bb * EQKV + e0 + r] = s;
}

// ---------------- Kernel 2: RoPE + scatter (unchanged) --------------------
__device__ __forceinline__ float rope_val(const float* src, int d, float pos) {
  int i = d & 63;
  float inv_freq = powf(10000.f, -(float)(2 * i) * (1.f / 128.f));
  float ang = pos * inv_freq;
  float s, c;
  sincosf(ang, &s, &c);
  float x = src[d];
  float rot = (d < 64) ? -src[d + 64] : src[d - 64];
  return x * c + rot * s;
}

__global__ void rope_scatter(const float* __restrict__ raw,
                             const void* __restrict__ pos_ids,
                             float* __restrict__ qout,
                             float* __restrict__ kc, float* __restrict__ vc) {
  const int b = blockIdx.y, j = blockIdx.x, d = threadIdx.x;  // 128 threads
  const int* pi = (const int*)pos_ids;
  long long pos = (pi[1] == 0 && pi[0] != 0) ? ((const long long*)pos_ids)[b]
                                             : (long long)pi[b];
  const float fpos = (float)pos;
  if (j < 32) {
    const float* src = raw + (size_t)b * EQKV + j * HD;
    qout[(size_t)b * (NH * HD) + j * HD + d] = rope_val(src, d, fpos);
  } else if (j < 40) {
    int kvh = j - 32;
    const float* src = raw + (size_t)b * EQKV + 4096 + kvh * HD;
    kc[(((size_t)b * NKV + kvh) * SEQ + PASTN) * HD + d] = rope_val(src, d, fpos);
  } else {
    int kvh = j - 40;
    vc[(((size_t)b * NKV + kvh) * SEQ + PASTN) * HD + d] =
        raw[(size_t)b * EQKV + 5120 + kvh * HD + d];
  }
}

// ---------------- Kernel 3: copy-shaped fused flash-decode -----------------
// grid (chunk=16, kv=8, b=16) = 2048 blocks; 4 waves/block; wave owns 64 rows.
// Each step streams a 2-row 1KB chunk of K and V with FULL-WAVE loads+stores
// (lane l covers bytes l*16 of the chunk). Lane computes dot-slices for all
// 4 heads; 32-lane shuffle reduce; uniform exact rescale-skip.
__global__ __launch_bounds__(256, 4) void attn_decode(
    const float* __restrict__ pastK, const float* __restrict__ pastV,
    const float* __restrict__ qv, const float* __restrict__ mask,
    float* __restrict__ kc, float* __restrict__ vc,
    float* __restrict__ part /* [B][32][NCHUNK][PSTRIDE] */) {
  __shared__ __align__(16) float sm[4][4][132];  // [wave][head][m,l,pad,ctx128]

  const int chunk = blockIdx.x, kv = blockIdx.y, b = blockIdx.z;
  const int tid = threadIdx.x, wid = tid >> 6, lane = tid & 63;
  const int half = lane >> 5, q32 = lane & 31;
  const int fo = q32 * 4;          // float offset within the lane's row
  const int lo = lane * 4;         // flat float offset within a 2-row chunk

  // Q: 4 heads, dims [fo, fo+4)
  v4f q[4];
  const float* qb = qv + (size_t)b * (NH * HD) + kv * 4 * HD + fo;
#pragma unroll
  for (int h = 0; h < 4; ++h) q[h] = *(const v4f*)(qb + h * HD);

  const size_t prow = ((size_t)b * NKV + kv) * PASTN;
  const size_t crow = ((size_t)b * NKV + kv) * SEQ;
  const int base = chunk * CHUNKS + wid * (CHUNKS / 4);
  const float* mrow = mask + (size_t)b * SEQ;

  float m[4], l[4];
  v4f c[4];
#pragma unroll
  for (int h = 0; h < 4; ++h) {
    m[h] = -1e30f; l[h] = 0.f;
    c[h] = (v4f){0.f, 0.f, 0.f, 0.f};
  }

  for (int t = 0; t < CHUNKS / 8; ++t) {   // 32 steps x 2 rows
    const int sp = base + t * 2;           // first row of the pair
    const int s = sp + half;               // lane's row
    v4f kch, vch;
    if (sp + 1 < PASTN) {                  // uniform fast path
      const float* kp = pastK + (prow + sp) * HD + lo;
      const float* vp = pastV + (prow + sp) * HD + lo;
      kch = __builtin_nontemporal_load((const v4f*)kp);
      vch = __builtin_nontemporal_load((const v4f*)vp);
      __builtin_nontemporal_store(kch, (v4f*)(kc + (crow + sp) * HD + lo));
      __builtin_nontemporal_store(vch, (v4f*)(vc + (crow + sp) * HD + lo));
    } else {                               // pair contains row 4095
      const float* kp = (s < PASTN) ? pastK + (prow + s) * HD + fo
                                    : kc + (crow + s) * HD + fo;
      const float* vp = (s < PASTN) ? pastV + (prow + s) * HD + fo
                                    : vc + (crow + s) * HD + fo;
      kch = *(const v4f*)kp;
      vch = *(const v4f*)vp;
      if (s < PASTN) {
        *(v4f*)(kc + (crow + s) * HD + fo) = kch;
        *(v4f*)(vc + (crow + s) * HD + fo) = vch;
      }
    }

    const float mval = mrow[s];
#pragma unroll
    for (int h = 0; h < 4; ++h) {
      v4f tv = q[h] * kch;
      float d = tv[0] + tv[1] + tv[2] + tv[3];
      d += __shfl_xor(d, 1);
      d += __shfl_xor(d, 2);
      d += __shfl_xor(d, 4);
      d += __shfl_xor(d, 8);
      d += __shfl_xor(d, 16);              // row-dot, uniform within half
      float sc = d * SCALE + mval;
      float gm = fmaxf(sc, __shfl_xor(sc, 32));  // pair max, wave-uniform
      if (gm > m[h]) {                     // exact skip: alpha==1 otherwise
        float alpha = __expf(m[h] - gm);
        l[h] *= alpha;
        c[h] *= alpha;
        m[h] = gm;
      }
      float p = __expf(sc - m[h]);
      l[h] += p;
      c[h] += p * vch;
    }
  }

  // merge the two row-halves (lane ^ 32)
#pragma unroll
  for (int h = 0; h < 4; ++h) {
    l[h] += __shfl_xor(l[h], 32);
#pragma unroll
    for (int j = 0; j < 4; ++j) c[h][j] += __shfl_xor(c[h][j], 32);
  }

  if (half == 0) {
#pragma unroll
    for (int h = 0; h < 4; ++h) {
      if (q32 == 0) { sm[wid][h][0] = m[h]; sm[wid][h][1] = l[h]; }
      *(v4f*)(&sm[wid][h][4 + fo]) = c[h];
    }
  }
  __syncthreads();

  // wave `wid` merges head `wid` across the 4 wave-slices
  float mstar = -1e30f;
#pragma unroll
  for (int sl = 0; sl < 4; ++sl) mstar = fmaxf(mstar, sm[sl][wid][0]);
  float den = 0.f;
  const int d2 = lane * 2;
  float nx = 0.f, ny = 0.f;
#pragma unroll
  for (int sl = 0; sl < 4; ++sl) {
    float w = __expf(sm[sl][wid][0] - mstar);
    den += w * sm[sl][wid][1];
    nx += w * sm[sl][wid][4 + d2];
    ny += w * sm[sl][wid][4 + d2 + 1];
  }
  float* pp = part + (((size_t)b * NH + kv * 4 + wid) * NCHUNK + chunk) * PSTRIDE;
  if (lane == 0) { pp[0] = mstar; pp[1] = den; }
  float2 nv = {nx, ny};
  *(float2*)(pp + 4 + d2) = nv;
}

// ---------------- Kernel 4: combine chunk partials ------------------------
__global__ void combine(const float* __restrict__ part, float* __restrict__ ctx) {
  const int bh = blockIdx.x;        // 0..511
  const int lane = threadIdx.x;     // 64
  const float* pp = part + (size_t)bh * NCHUNK * PSTRIDE;
  float mstar = -1e30f;
#pragma unroll
  for (int c = 0; c < NCHUNK; ++c) mstar = fmaxf(mstar, pp[c * PSTRIDE]);
  float den = 0.f, nx = 0.f, ny = 0.f;
  const int d2 = lane * 2;
#pragma unroll
  for (int c = 0; c < NCHUNK; ++c) {
    float w = __expf(pp[c * PSTRIDE] - mstar);
    den += w * pp[c * PSTRIDE + 1];
    float2 pv = *(const float2*)(pp + c * PSTRIDE + 4 + d2);
    nx += w * pv.x;
    ny += w * pv.y;
  }
  float inv = 1.0f / den;
  ctx[(size_t)bh * HD + d2] = nx * inv;
  ctx[(size_t)bh * HD + d2 + 1] = ny * inv;
}

// ---------------- Kernel 5: output projection (R6 form, unchanged) --------
__global__ __launch_bounds__(256) void out_proj(
    const float* __restrict__ ctx, const float* __restrict__ Wo,
    float* __restrict__ out) {
  __shared__ __align__(16) float smem[4 * 32 * 65];
  const int tid = threadIdx.x, wid = tid >> 6, lane = tid & 63;
  const int e0 = blockIdx.x * 16 + wid * 4;

  float acc[4][16];
#pragma unroll
  for (int r = 0; r < 4; ++r)
#pragma unroll
    for (int b = 0; b < 16; ++b) acc[r][b] = 0.f;

  float* ld = smem;  // [16][256]
  for (int k0 = 0; k0 < DMODEL; k0 += 256) {
    __syncthreads();
#pragma unroll
    for (int i = 0; i < 4; ++i) {
      int flat = i * 1024 + tid * 4;
      int bb = flat >> 8, c = flat & 255;
      *(v4f*)(&ld[bb * 256 + c]) = *(const v4f*)(ctx + (size_t)bb * DMODEL + k0 + c);
    }
    __syncthreads();
    v4f w4[4];
#pragma unroll
    for (int r = 0; r < 4; ++r)
      w4[r] = *(const v4f*)(Wo + (size_t)(e0 + r) * DMODEL + k0 + lane * 4);
#pragma unroll
    for (int b = 0; b < 16; ++b) {
      v4f h4 = *(const v4f*)(&ld[b * 256 + lane * 4]);
#pragma unroll
      for (int r = 0; r < 4; ++r) {
        v4f t = w4[r] * h4;
        acc[r][b] += t[0] + t[1] + t[2] + t[3];
      }
    }
  }

#pragma unroll
  for (int r = 0; r < 4; ++r)
#pragma unroll
    for (int b = 0; b < 16; ++b) acc[r][b] += __shfl_xor(acc[r][b], 32);

  __syncthreads();
  if (lane < 32) {
#pragma unroll
    for (int r = 0; r < 4; ++r)
#pragma unroll
      for (int b = 0; b < 16; ++b)
        smem[(wid * 32 + lane) * 65 + r * 16 + b] = acc[r][b];
  }
  __syncthreads();
  float s = 0.f;
#pragma unroll
  for (int t2 = 0; t2 < 32; ++t2) s += smem[(wid * 32 + t2) * 65 + lane];
  const int r = lane >> 4, bb = lane & 15;
  out[(size_t)bb * DMODEL + e0 + r] = s;
}

// ---------------------------------------------------------------------------
extern "C" void kernel_launch(void* const* d_in, const int* in_sizes, int n_in,
                              void* d_out, int out_size, void* d_ws, size_t ws_size,
                              hipStream_t stream) {
  const float* hs    = (const float*)d_in[0];
  const float* mask  = (const float*)d_in[1];
  const void*  pos   = d_in[2];
  const float* pastK = (const float*)d_in[3];
  const float* pastV = (const float*)d_in[4];
  const float* Wq    = (const float*)d_in[5];
  const float* Wk    = (const float*)d_in[6];
  const float* Wv    = (const float*)d_in[7];
  const float* Wo    = (const float*)d_in[8];

  float* out  = (float*)d_out;
  float* attn = out;                                        // 16*4096
  float* kc   = out + (size_t)NB * DMODEL;                  // 16*8*4096*128
  float* vc   = kc + (size_t)NB * NKV * SEQ * HD;

  float* ws      = (float*)d_ws;
  float* ws_q    = ws;                                         // 65536
  float* ws_raw  = ws_q + (size_t)NB * NH * HD;                // 16*6144
  float* ws_part = ws_raw + (size_t)NB * EQKV;                 // 16*32*16*136
  float* ws_ctx  = ws_part + (size_t)NB * NH * NCHUNK * PSTRIDE; // 65536

  qkv_proj<<<EQKV / 16, 256, 0, stream>>>(hs, Wq, Wk, Wv, ws_raw);
  rope_scatter<<<dim3(48, NB), 128, 0, stream>>>(ws_raw, pos, ws_q, kc, vc);
  attn_decode<<<dim3(NCHUNK, NKV, NB), 256, 0, stream>>>(pastK, pastV, ws_q, mask,
                                                         kc, vc, ws_part);
  combine<<<NB * NH, 64, 0, stream>>>(ws_part, ws_ctx);
  out_proj<<<DMODEL / 16, 256, 0, stream>>>(ws_ctx, Wo, attn);
}

// Round 8
// 294.816 us; speedup vs baseline: 2.1360x; 1.0822x over previous
//
#include <hip/hip_runtime.h>

#define NB 16
#define DMODEL 4096
#define NH 32
#define NKV 8
#define HD 128
#define SEQ 4096
#define PASTN 4095
#define EQKV 6144           // 4096 q + 1024 k + 1024 v rows
#define NCHUNK 16
#define CHUNKS 256          // rows per chunk-block (SEQ/NCHUNK)
#define PSTRIDE 136         // partials stride (16B aligned)
#define SCALE 0.08838834764831845f  // 1/sqrt(128)

typedef float v4f __attribute__((ext_vector_type(4)));

// ---------------- Kernel 1: QKV projection, 8 rows/block (2/wave) ----------
// grid 768 blocks -> 3 blocks/CU, 12 waves/CU.
__global__ __launch_bounds__(256) void qkv_proj(
    const float* __restrict__ hs, const float* __restrict__ Wq,
    const float* __restrict__ Wk, const float* __restrict__ Wv,
    float* __restrict__ raw /* [B][6144] */) {
  __shared__ __align__(16) float smem[4 * 32 * 33];  // 16.9KB; ld-stage then red
  const int tid = threadIdx.x, wid = tid >> 6, lane = tid & 63;
  const int e0 = blockIdx.x * 8 + wid * 2;

  const float* wrow[2];
#pragma unroll
  for (int r = 0; r < 2; ++r) {
    int e = e0 + r;
    wrow[r] = (e < 4096) ? (Wq + (size_t)e * DMODEL)
            : (e < 5120) ? (Wk + (size_t)(e - 4096) * DMODEL)
                         : (Wv + (size_t)(e - 5120) * DMODEL);
  }

  float acc[2][16];
#pragma unroll
  for (int r = 0; r < 2; ++r)
#pragma unroll
    for (int b = 0; b < 16; ++b) acc[r][b] = 0.f;

  float* ld = smem;  // [16][256]
  for (int k0 = 0; k0 < DMODEL; k0 += 256) {
    __syncthreads();
#pragma unroll
    for (int i = 0; i < 4; ++i) {
      int flat = i * 1024 + tid * 4;
      int bb = flat >> 8, c = flat & 255;
      *(v4f*)(&ld[bb * 256 + c]) = *(const v4f*)(hs + (size_t)bb * DMODEL + k0 + c);
    }
    __syncthreads();
    v4f w4[2];
#pragma unroll
    for (int r = 0; r < 2; ++r) w4[r] = *(const v4f*)(wrow[r] + k0 + lane * 4);
#pragma unroll
    for (int b = 0; b < 16; ++b) {
      v4f h4 = *(const v4f*)(&ld[b * 256 + lane * 4]);
#pragma unroll
      for (int r = 0; r < 2; ++r) {
        v4f t = w4[r] * h4;
        acc[r][b] += t[0] + t[1] + t[2] + t[3];
      }
    }
  }

#pragma unroll
  for (int r = 0; r < 2; ++r)
#pragma unroll
    for (int b = 0; b < 16; ++b) acc[r][b] += __shfl_xor(acc[r][b], 32);

  __syncthreads();
  if (lane < 32) {
#pragma unroll
    for (int r = 0; r < 2; ++r)
#pragma unroll
      for (int b = 0; b < 16; ++b)
        smem[(wid * 32 + lane) * 33 + r * 16 + b] = acc[r][b];
  }
  __syncthreads();
  if (lane < 32) {
    float s = 0.f;
#pragma unroll
    for (int t2 = 0; t2 < 32; ++t2) s += smem[(wid * 32 + t2) * 33 + lane];
    const int r = lane >> 4, bb = lane & 15;
    raw[(size_t)bb * EQKV + e0 + r] = s;
  }
}

// ---------------- Kernel 2: RoPE + scatter (unchanged) --------------------
__device__ __forceinline__ float rope_val(const float* src, int d, float pos) {
  int i = d & 63;
  float inv_freq = powf(10000.f, -(float)(2 * i) * (1.f / 128.f));
  float ang = pos * inv_freq;
  float s, c;
  sincosf(ang, &s, &c);
  float x = src[d];
  float rot = (d < 64) ? -src[d + 64] : src[d - 64];
  return x * c + rot * s;
}

__global__ void rope_scatter(const float* __restrict__ raw,
                             const void* __restrict__ pos_ids,
                             float* __restrict__ qout,
                             float* __restrict__ kc, float* __restrict__ vc) {
  const int b = blockIdx.y, j = blockIdx.x, d = threadIdx.x;  // 128 threads
  const int* pi = (const int*)pos_ids;
  long long pos = (pi[1] == 0 && pi[0] != 0) ? ((const long long*)pos_ids)[b]
                                             : (long long)pi[b];
  const float fpos = (float)pos;
  if (j < 32) {
    const float* src = raw + (size_t)b * EQKV + j * HD;
    qout[(size_t)b * (NH * HD) + j * HD + d] = rope_val(src, d, fpos);
  } else if (j < 40) {
    int kvh = j - 32;
    const float* src = raw + (size_t)b * EQKV + 4096 + kvh * HD;
    kc[(((size_t)b * NKV + kvh) * SEQ + PASTN) * HD + d] = rope_val(src, d, fpos);
  } else {
    int kvh = j - 40;
    vc[(((size_t)b * NKV + kvh) * SEQ + PASTN) * HD + d] =
        raw[(size_t)b * EQKV + 5120 + kvh * HD + d];
  }
}

// ---------------- Kernel 3: prefetched copy-shaped flash-decode ------------
// grid (16,8,16) = 2048 blocks; 4 waves/block; wave owns 64 rows.
// 2-deep register prefetch; per-half independent online softmax; mask
// preloaded once per wave. Per-lane address select (no branchy dual path).
__global__ __launch_bounds__(256, 4) void attn_decode(
    const float* __restrict__ pastK, const float* __restrict__ pastV,
    const float* __restrict__ qv, const float* __restrict__ mask,
    float* __restrict__ kc, float* __restrict__ vc,
    float* __restrict__ part /* [B][32][NCHUNK][PSTRIDE] */) {
  __shared__ __align__(16) float sm[4][4][132];  // [wave][head][m,l,pad,ctx128]

  const int chunk = blockIdx.x, kv = blockIdx.y, b = blockIdx.z;
  const int tid = threadIdx.x, wid = tid >> 6, lane = tid & 63;
  const int half = lane >> 5, q32 = lane & 31;
  const int fo = q32 * 4;          // float offset within the lane's row

  v4f q[4];
  const float* qb = qv + (size_t)b * (NH * HD) + kv * 4 * HD + fo;
#pragma unroll
  for (int h = 0; h < 4; ++h) q[h] = *(const v4f*)(qb + h * HD);

  const size_t prow = ((size_t)b * NKV + kv) * PASTN;
  const size_t crow = ((size_t)b * NKV + kv) * SEQ;
  const int base = chunk * CHUNKS + wid * (CHUNKS / 4);
  const float* mrow = mask + (size_t)b * SEQ;

  // mask preload: lane L holds mask[base + 2*(L&31) + (L>>5)];
  // step t's value for this lane sits at source lane t | (lane & 32).
  const float mreg = mrow[base + 2 * q32 + half];

  float m[4], l[4];
  v4f c[4];
#pragma unroll
  for (int h = 0; h < 4; ++h) {
    m[h] = -1e30f; l[h] = 0.f;
    c[h] = (v4f){0.f, 0.f, 0.f, 0.f};
  }

  v4f kq[2], vq[2];
  // prologue: pairs 0 and 1
#pragma unroll
  for (int i = 0; i < 2; ++i) {
    const int s = base + 2 * i + half;
    const float* kp = (s < PASTN) ? pastK + (prow + s) * HD + fo
                                  : kc + (crow + s) * HD + fo;
    const float* vp = (s < PASTN) ? pastV + (prow + s) * HD + fo
                                  : vc + (crow + s) * HD + fo;
    kq[i] = __builtin_nontemporal_load((const v4f*)kp);
    vq[i] = __builtin_nontemporal_load((const v4f*)vp);
  }

#pragma unroll 2
  for (int t = 0; t < 32; ++t) {
    const int sp = base + 2 * t;
    const int s = sp + half;
    const v4f kch = kq[t & 1], vch = vq[t & 1];
    if (t < 30) {  // prefetch pair t+2 into the freed slot
      const int s2 = sp + 4 + half;
      const float* kp = (s2 < PASTN) ? pastK + (prow + s2) * HD + fo
                                     : kc + (crow + s2) * HD + fo;
      const float* vp = (s2 < PASTN) ? pastV + (prow + s2) * HD + fo
                                     : vc + (crow + s2) * HD + fo;
      kq[t & 1] = __builtin_nontemporal_load((const v4f*)kp);
      vq[t & 1] = __builtin_nontemporal_load((const v4f*)vp);
    }
    // write-through cache copy (exec-masked only for row 4095)
    if (s < PASTN) {
      __builtin_nontemporal_store(kch, (v4f*)(kc + (crow + s) * HD + fo));
      __builtin_nontemporal_store(vch, (v4f*)(vc + (crow + s) * HD + fo));
    }

    const float mval = __shfl(mreg, t | (lane & 32));
#pragma unroll
    for (int h = 0; h < 4; ++h) {
      v4f tv = q[h] * kch;
      float d = tv[0] + tv[1] + tv[2] + tv[3];
      d += __shfl_xor(d, 1);
      d += __shfl_xor(d, 2);
      d += __shfl_xor(d, 4);
      d += __shfl_xor(d, 8);
      d += __shfl_xor(d, 16);              // row-dot, uniform within half
      float sc = d * SCALE + mval;
      if (sc > m[h]) {                     // per-half online max (exact)
        float alpha = __expf(m[h] - sc);
        l[h] *= alpha;
        c[h] *= alpha;
        m[h] = sc;
      }
      float p = __expf(sc - m[h]);
      l[h] += p;
      c[h] += p * vch;
    }
  }

  // merge the two half-streams (lane ^ 32) with rescale
#pragma unroll
  for (int h = 0; h < 4; ++h) {
    float mo = __shfl_xor(m[h], 32);
    float mn = fmaxf(m[h], mo);
    float f = __expf(m[h] - mn);
    l[h] *= f;
    c[h] *= f;
    l[h] += __shfl_xor(l[h], 32);
#pragma unroll
    for (int j = 0; j < 4; ++j) c[h][j] += __shfl_xor(c[h][j], 32);
    m[h] = mn;
  }

  if (half == 0) {
#pragma unroll
    for (int h = 0; h < 4; ++h) {
      if (q32 == 0) { sm[wid][h][0] = m[h]; sm[wid][h][1] = l[h]; }
      *(v4f*)(&sm[wid][h][4 + fo]) = c[h];
    }
  }
  __syncthreads();

  // wave `wid` merges head `wid` across the 4 wave-slices
  float mstar = -1e30f;
#pragma unroll
  for (int sl = 0; sl < 4; ++sl) mstar = fmaxf(mstar, sm[sl][wid][0]);
  float den = 0.f;
  const int d2 = lane * 2;
  float nx = 0.f, ny = 0.f;
#pragma unroll
  for (int sl = 0; sl < 4; ++sl) {
    float w = __expf(sm[sl][wid][0] - mstar);
    den += w * sm[sl][wid][1];
    nx += w * sm[sl][wid][4 + d2];
    ny += w * sm[sl][wid][4 + d2 + 1];
  }
  float* pp = part + (((size_t)b * NH + kv * 4 + wid) * NCHUNK + chunk) * PSTRIDE;
  if (lane == 0) { pp[0] = mstar; pp[1] = den; }
  float2 nv = {nx, ny};
  *(float2*)(pp + 4 + d2) = nv;
}

// ---------------- Kernel 4: combine chunk partials ------------------------
__global__ void combine(const float* __restrict__ part, float* __restrict__ ctx) {
  const int bh = blockIdx.x;        // 0..511
  const int lane = threadIdx.x;     // 64
  const float* pp = part + (size_t)bh * NCHUNK * PSTRIDE;
  float mstar = -1e30f;
#pragma unroll
  for (int c = 0; c < NCHUNK; ++c) mstar = fmaxf(mstar, pp[c * PSTRIDE]);
  float den = 0.f, nx = 0.f, ny = 0.f;
  const int d2 = lane * 2;
#pragma unroll
  for (int c = 0; c < NCHUNK; ++c) {
    float w = __expf(pp[c * PSTRIDE] - mstar);
    den += w * pp[c * PSTRIDE + 1];
    float2 pv = *(const float2*)(pp + c * PSTRIDE + 4 + d2);
    nx += w * pv.x;
    ny += w * pv.y;
  }
  float inv = 1.0f / den;
  ctx[(size_t)bh * HD + d2] = nx * inv;
  ctx[(size_t)bh * HD + d2 + 1] = ny * inv;
}

// ---------------- Kernel 5: output projection, 8 rows/block ----------------
// grid 512 blocks -> 2 blocks/CU, 8 waves/CU.
__global__ __launch_bounds__(256) void out_proj(
    const float* __restrict__ ctx, const float* __restrict__ Wo,
    float* __restrict__ out) {
  __shared__ __align__(16) float smem[4 * 32 * 33];
  const int tid = threadIdx.x, wid = tid >> 6, lane = tid & 63;
  const int e0 = blockIdx.x * 8 + wid * 2;

  float acc[2][16];
#pragma unroll
  for (int r = 0; r < 2; ++r)
#pragma unroll
    for (int b = 0; b < 16; ++b) acc[r][b] = 0.f;

  float* ld = smem;  // [16][256]
  for (int k0 = 0; k0 < DMODEL; k0 += 256) {
    __syncthreads();
#pragma unroll
    for (int i = 0; i < 4; ++i) {
      int flat = i * 1024 + tid * 4;
      int bb = flat >> 8, c = flat & 255;
      *(v4f*)(&ld[bb * 256 + c]) = *(const v4f*)(ctx + (size_t)bb * DMODEL + k0 + c);
    }
    __syncthreads();
    v4f w4[2];
#pragma unroll
    for (int r = 0; r < 2; ++r)
      w4[r] = *(const v4f*)(Wo + (size_t)(e0 + r) * DMODEL + k0 + lane * 4);
#pragma unroll
    for (int b = 0; b < 16; ++b) {
      v4f h4 = *(const v4f*)(&ld[b * 256 + lane * 4]);
#pragma unroll
      for (int r = 0; r < 2; ++r) {
        v4f t = w4[r] * h4;
        acc[r][b] += t[0] + t[1] + t[2] + t[3];
      }
    }
  }

#pragma unroll
  for (int r = 0; r < 2; ++r)
#pragma unroll
    for (int b = 0; b < 16; ++b) acc[r][b] += __shfl_xor(acc[r][b], 32);

  __syncthreads();
  if (lane < 32) {
#pragma unroll
    for (int r = 0; r < 2; ++r)
#pragma unroll
      for (int b = 0; b < 16; ++b)
        smem[(wid * 32 + lane) * 33 + r * 16 + b] = acc[r][b];
  }
  __syncthreads();
  if (lane < 32) {
    float s = 0.f;
#pragma unroll
    for (int t2 = 0; t2 < 32; ++t2) s += smem[(wid * 32 + t2) * 33 + lane];
    const int r = lane >> 4, bb = lane & 15;
    out[(size_t)bb * DMODEL + e0 + r] = s;
  }
}

// ---------------------------------------------------------------------------
extern "C" void kernel_launch(void* const* d_in, const int* in_sizes, int n_in,
                              void* d_out, int out_size, void* d_ws, size_t ws_size,
                              hipStream_t stream) {
  const float* hs    = (const float*)d_in[0];
  const float* mask  = (const float*)d_in[1];
  const void*  pos   = d_in[2];
  const float* pastK = (const float*)d_in[3];
  const float* pastV = (const float*)d_in[4];
  const float* Wq    = (const float*)d_in[5];
  const float* Wk    = (const float*)d_in[6];
  const float* Wv    = (const float*)d_in[7];
  const float* Wo    = (const float*)d_in[8];

  float* out  = (float*)d_out;
  float* attn = out;                                        // 16*4096
  float* kc   = out + (size_t)NB * DMODEL;                  // 16*8*4096*128
  float* vc   = kc + (size_t)NB * NKV * SEQ * HD;

  float* ws      = (float*)d_ws;
  float* ws_q    = ws;                                         // 65536
  float* ws_raw  = ws_q + (size_t)NB * NH * HD;                // 16*6144
  float* ws_part = ws_raw + (size_t)NB * EQKV;                 // 16*32*16*136
  float* ws_ctx  = ws_part + (size_t)NB * NH * NCHUNK * PSTRIDE; // 65536

  qkv_proj<<<EQKV / 8, 256, 0, stream>>>(hs, Wq, Wk, Wv, ws_raw);
  rope_scatter<<<dim3(48, NB), 128, 0, stream>>>(ws_raw, pos, ws_q, kc, vc);
  attn_decode<<<dim3(NCHUNK, NKV, NB), 256, 0, stream>>>(pastK, pastV, ws_q, mask,
                                                         kc, vc, ws_part);
  combine<<<NB * NH, 64, 0, stream>>>(ws_part, ws_ctx);
  out_proj<<<DMODEL / 8, 256, 0, stream>>>(ws_ctx, Wo, attn);
}

// Round 9
// 289.407 us; speedup vs baseline: 2.1759x; 1.0187x over previous
//
#include <hip/hip_runtime.h>

#define NB 16
#define DMODEL 4096
#define NH 32
#define NKV 8
#define HD 128
#define SEQ 4096
#define PASTN 4095
#define EQKV 6144           // 4096 q + 1024 k + 1024 v rows
#define NCHUNK 16
#define CHUNKS 256          // rows per chunk-block (SEQ/NCHUNK)
#define PSTRIDE 136         // partials stride (16B aligned)
#define SCALE 0.08838834764831845f  // 1/sqrt(128)

typedef float v4f __attribute__((ext_vector_type(4)));

// ---------------- Kernel 1: QKV projection, 8 rows/block (2/wave) ----------
__global__ __launch_bounds__(256) void qkv_proj(
    const float* __restrict__ hs, const float* __restrict__ Wq,
    const float* __restrict__ Wk, const float* __restrict__ Wv,
    float* __restrict__ raw /* [B][6144] */) {
  __shared__ __align__(16) float smem[4 * 32 * 33];
  const int tid = threadIdx.x, wid = tid >> 6, lane = tid & 63;
  const int e0 = blockIdx.x * 8 + wid * 2;

  const float* wrow[2];
#pragma unroll
  for (int r = 0; r < 2; ++r) {
    int e = e0 + r;
    wrow[r] = (e < 4096) ? (Wq + (size_t)e * DMODEL)
            : (e < 5120) ? (Wk + (size_t)(e - 4096) * DMODEL)
                         : (Wv + (size_t)(e - 5120) * DMODEL);
  }

  float acc[2][16];
#pragma unroll
  for (int r = 0; r < 2; ++r)
#pragma unroll
    for (int b = 0; b < 16; ++b) acc[r][b] = 0.f;

  float* ld = smem;  // [16][256]
  for (int k0 = 0; k0 < DMODEL; k0 += 256) {
    __syncthreads();
#pragma unroll
    for (int i = 0; i < 4; ++i) {
      int flat = i * 1024 + tid * 4;
      int bb = flat >> 8, c = flat & 255;
      *(v4f*)(&ld[bb * 256 + c]) = *(const v4f*)(hs + (size_t)bb * DMODEL + k0 + c);
    }
    __syncthreads();
    v4f w4[2];
#pragma unroll
    for (int r = 0; r < 2; ++r) w4[r] = *(const v4f*)(wrow[r] + k0 + lane * 4);
#pragma unroll
    for (int b = 0; b < 16; ++b) {
      v4f h4 = *(const v4f*)(&ld[b * 256 + lane * 4]);
#pragma unroll
      for (int r = 0; r < 2; ++r) {
        v4f t = w4[r] * h4;
        acc[r][b] += t[0] + t[1] + t[2] + t[3];
      }
    }
  }

#pragma unroll
  for (int r = 0; r < 2; ++r)
#pragma unroll
    for (int b = 0; b < 16; ++b) acc[r][b] += __shfl_xor(acc[r][b], 32);

  __syncthreads();
  if (lane < 32) {
#pragma unroll
    for (int r = 0; r < 2; ++r)
#pragma unroll
      for (int b = 0; b < 16; ++b)
        smem[(wid * 32 + lane) * 33 + r * 16 + b] = acc[r][b];
  }
  __syncthreads();
  if (lane < 32) {
    float s = 0.f;
#pragma unroll
    for (int t2 = 0; t2 < 32; ++t2) s += smem[(wid * 32 + t2) * 33 + lane];
    const int r = lane >> 4, bb = lane & 15;
    raw[(size_t)bb * EQKV + e0 + r] = s;
  }
}

// ---------------- Kernel 2: RoPE + scatter (unchanged) --------------------
__device__ __forceinline__ float rope_val(const float* src, int d, float pos) {
  int i = d & 63;
  float inv_freq = powf(10000.f, -(float)(2 * i) * (1.f / 128.f));
  float ang = pos * inv_freq;
  float s, c;
  sincosf(ang, &s, &c);
  float x = src[d];
  float rot = (d < 64) ? -src[d + 64] : src[d - 64];
  return x * c + rot * s;
}

__global__ void rope_scatter(const float* __restrict__ raw,
                             const void* __restrict__ pos_ids,
                             float* __restrict__ qout,
                             float* __restrict__ kc, float* __restrict__ vc) {
  const int b = blockIdx.y, j = blockIdx.x, d = threadIdx.x;  // 128 threads
  const int* pi = (const int*)pos_ids;
  long long pos = (pi[1] == 0 && pi[0] != 0) ? ((const long long*)pos_ids)[b]
                                             : (long long)pi[b];
  const float fpos = (float)pos;
  if (j < 32) {
    const float* src = raw + (size_t)b * EQKV + j * HD;
    qout[(size_t)b * (NH * HD) + j * HD + d] = rope_val(src, d, fpos);
  } else if (j < 40) {
    int kvh = j - 32;
    const float* src = raw + (size_t)b * EQKV + 4096 + kvh * HD;
    kc[(((size_t)b * NKV + kvh) * SEQ + PASTN) * HD + d] = rope_val(src, d, fpos);
  } else {
    int kvh = j - 40;
    vc[(((size_t)b * NKV + kvh) * SEQ + PASTN) * HD + d] =
        raw[(size_t)b * EQKV + 5120 + kvh * HD + d];
  }
}

// ---------------- Kernel 3: deep-prefetch copy-shaped flash-decode ---------
// grid (16,8,16) = 2048 blocks; 4 waves/block; wave owns 64 rows.
// 4-deep register prefetch, ILP-batched head dots, per-half online softmax.
__global__ __launch_bounds__(256, 4) void attn_decode(
    const float* __restrict__ pastK, const float* __restrict__ pastV,
    const float* __restrict__ qv, const float* __restrict__ mask,
    float* __restrict__ kc, float* __restrict__ vc,
    float* __restrict__ part /* [B][32][NCHUNK][PSTRIDE] */) {
  __shared__ __align__(16) float sm[4][4][132];  // [wave][head][m,l,pad,ctx128]

  const int chunk = blockIdx.x, kv = blockIdx.y, b = blockIdx.z;
  const int tid = threadIdx.x, wid = tid >> 6, lane = tid & 63;
  const int half = lane >> 5, q32 = lane & 31;
  const int fo = q32 * 4;          // float offset within the lane's row

  v4f q[4];
  const float* qb = qv + (size_t)b * (NH * HD) + kv * 4 * HD + fo;
#pragma unroll
  for (int h = 0; h < 4; ++h) q[h] = *(const v4f*)(qb + h * HD);

  const size_t prow = ((size_t)b * NKV + kv) * PASTN;
  const size_t crow = ((size_t)b * NKV + kv) * SEQ;
  const int base = chunk * CHUNKS + wid * (CHUNKS / 4);
  const float* mrow = mask + (size_t)b * SEQ;

  // mask preload: lane L holds mask[base + 2*(L&31) + (L>>5)];
  // step t's value for this lane sits at source lane t | (lane & 32).
  const float mreg = mrow[base + 2 * q32 + half];

  float m[4], l[4];
  v4f c[4];
#pragma unroll
  for (int h = 0; h < 4; ++h) {
    m[h] = -1e30f; l[h] = 0.f;
    c[h] = (v4f){0.f, 0.f, 0.f, 0.f};
  }

  v4f kq[4], vq[4];
  // prologue: pairs 0..3
#pragma unroll
  for (int i = 0; i < 4; ++i) {
    const int s = base + 2 * i + half;
    const float* kp = (s < PASTN) ? pastK + (prow + s) * HD + fo
                                  : kc + (crow + s) * HD + fo;
    const float* vp = (s < PASTN) ? pastV + (prow + s) * HD + fo
                                  : vc + (crow + s) * HD + fo;
    kq[i] = __builtin_nontemporal_load((const v4f*)kp);
    vq[i] = __builtin_nontemporal_load((const v4f*)vp);
  }

#pragma unroll 4
  for (int t = 0; t < 32; ++t) {
    const int sp = base + 2 * t;
    const int s = sp + half;
    const v4f kch = kq[t & 3], vch = vq[t & 3];
    if (t < 28) {  // prefetch pair t+4 into the freed slot
      const int s2 = sp + 8 + half;
      const float* kp = (s2 < PASTN) ? pastK + (prow + s2) * HD + fo
                                     : kc + (crow + s2) * HD + fo;
      const float* vp = (s2 < PASTN) ? pastV + (prow + s2) * HD + fo
                                     : vc + (crow + s2) * HD + fo;
      kq[t & 3] = __builtin_nontemporal_load((const v4f*)kp);
      vq[t & 3] = __builtin_nontemporal_load((const v4f*)vp);
    }
    // write-through cache copy (exec-masked only for row 4095)
    if (s < PASTN) {
      __builtin_nontemporal_store(kch, (v4f*)(kc + (crow + s) * HD + fo));
      __builtin_nontemporal_store(vch, (v4f*)(vc + (crow + s) * HD + fo));
    }

    const float mval = __shfl(mreg, t | (lane & 32));

    // batched dots: 4 independent shuffles per level (DS-pipe ILP)
    float d4[4];
#pragma unroll
    for (int h = 0; h < 4; ++h) {
      v4f tv = q[h] * kch;
      d4[h] = tv[0] + tv[1] + tv[2] + tv[3];
    }
#pragma unroll
    for (int off = 1; off <= 16; off <<= 1)
#pragma unroll
      for (int h = 0; h < 4; ++h) d4[h] += __shfl_xor(d4[h], off);

#pragma unroll
    for (int h = 0; h < 4; ++h) {
      float sc = d4[h] * SCALE + mval;
      if (sc > m[h]) {                     // per-half online max (exact)
        float alpha = __expf(m[h] - sc);
        l[h] *= alpha;
        c[h] *= alpha;
        m[h] = sc;
      }
      float p = __expf(sc - m[h]);
      l[h] += p;
      c[h] += p * vch;
    }
  }

  // merge the two half-streams (lane ^ 32) with rescale
#pragma unroll
  for (int h = 0; h < 4; ++h) {
    float mo = __shfl_xor(m[h], 32);
    float mn = fmaxf(m[h], mo);
    float f = __expf(m[h] - mn);
    l[h] *= f;
    c[h] *= f;
    l[h] += __shfl_xor(l[h], 32);
#pragma unroll
    for (int j = 0; j < 4; ++j) c[h][j] += __shfl_xor(c[h][j], 32);
    m[h] = mn;
  }

  if (half == 0) {
#pragma unroll
    for (int h = 0; h < 4; ++h) {
      if (q32 == 0) { sm[wid][h][0] = m[h]; sm[wid][h][1] = l[h]; }
      *(v4f*)(&sm[wid][h][4 + fo]) = c[h];
    }
  }
  __syncthreads();

  // wave `wid` merges head `wid` across the 4 wave-slices
  float mstar = -1e30f;
#pragma unroll
  for (int sl = 0; sl < 4; ++sl) mstar = fmaxf(mstar, sm[sl][wid][0]);
  float den = 0.f;
  const int d2 = lane * 2;
  float nx = 0.f, ny = 0.f;
#pragma unroll
  for (int sl = 0; sl < 4; ++sl) {
    float w = __expf(sm[sl][wid][0] - mstar);
    den += w * sm[sl][wid][1];
    nx += w * sm[sl][wid][4 + d2];
    ny += w * sm[sl][wid][4 + d2 + 1];
  }
  float* pp = part + (((size_t)b * NH + kv * 4 + wid) * NCHUNK + chunk) * PSTRIDE;
  if (lane == 0) { pp[0] = mstar; pp[1] = den; }
  float2 nv = {nx, ny};
  *(float2*)(pp + 4 + d2) = nv;
}

// ---------------- Kernel 4: combine chunk partials ------------------------
__global__ void combine(const float* __restrict__ part, float* __restrict__ ctx) {
  const int bh = blockIdx.x;        // 0..511
  const int lane = threadIdx.x;     // 64
  const float* pp = part + (size_t)bh * NCHUNK * PSTRIDE;
  float mstar = -1e30f;
#pragma unroll
  for (int c = 0; c < NCHUNK; ++c) mstar = fmaxf(mstar, pp[c * PSTRIDE]);
  float den = 0.f, nx = 0.f, ny = 0.f;
  const int d2 = lane * 2;
#pragma unroll
  for (int c = 0; c < NCHUNK; ++c) {
    float w = __expf(pp[c * PSTRIDE] - mstar);
    den += w * pp[c * PSTRIDE + 1];
    float2 pv = *(const float2*)(pp + c * PSTRIDE + 4 + d2);
    nx += w * pv.x;
    ny += w * pv.y;
  }
  float inv = 1.0f / den;
  ctx[(size_t)bh * HD + d2] = nx * inv;
  ctx[(size_t)bh * HD + d2 + 1] = ny * inv;
}

// ---------------- Kernel 5: output projection, 8 rows/block ----------------
__global__ __launch_bounds__(256) void out_proj(
    const float* __restrict__ ctx, const float* __restrict__ Wo,
    float* __restrict__ out) {
  __shared__ __align__(16) float smem[4 * 32 * 33];
  const int tid = threadIdx.x, wid = tid >> 6, lane = tid & 63;
  const int e0 = blockIdx.x * 8 + wid * 2;

  float acc[2][16];
#pragma unroll
  for (int r = 0; r < 2; ++r)
#pragma unroll
    for (int b = 0; b < 16; ++b) acc[r][b] = 0.f;

  float* ld = smem;  // [16][256]
  for (int k0 = 0; k0 < DMODEL; k0 += 256) {
    __syncthreads();
#pragma unroll
    for (int i = 0; i < 4; ++i) {
      int flat = i * 1024 + tid * 4;
      int bb = flat >> 8, c = flat & 255;
      *(v4f*)(&ld[bb * 256 + c]) = *(const v4f*)(ctx + (size_t)bb * DMODEL + k0 + c);
    }
    __syncthreads();
    v4f w4[2];
#pragma unroll
    for (int r = 0; r < 2; ++r)
      w4[r] = *(const v4f*)(Wo + (size_t)(e0 + r) * DMODEL + k0 + lane * 4);
#pragma unroll
    for (int b = 0; b < 16; ++b) {
      v4f h4 = *(const v4f*)(&ld[b * 256 + lane * 4]);
#pragma unroll
      for (int r = 0; r < 2; ++r) {
        v4f t = w4[r] * h4;
        acc[r][b] += t[0] + t[1] + t[2] + t[3];
      }
    }
  }

#pragma unroll
  for (int r = 0; r < 2; ++r)
#pragma unroll
    for (int b = 0; b < 16; ++b) acc[r][b] += __shfl_xor(acc[r][b], 32);

  __syncthreads();
  if (lane < 32) {
#pragma unroll
    for (int r = 0; r < 2; ++r)
#pragma unroll
      for (int b = 0; b < 16; ++b)
        smem[(wid * 32 + lane) * 33 + r * 16 + b] = acc[r][b];
  }
  __syncthreads();
  if (lane < 32) {
    float s = 0.f;
#pragma unroll
    for (int t2 = 0; t2 < 32; ++t2) s += smem[(wid * 32 + t2) * 33 + lane];
    const int r = lane >> 4, bb = lane & 15;
    out[(size_t)bb * DMODEL + e0 + r] = s;
  }
}

// ---------------------------------------------------------------------------
extern "C" void kernel_launch(void* const* d_in, const int* in_sizes, int n_in,
                              void* d_out, int out_size, void* d_ws, size_t ws_size,
                              hipStream_t stream) {
  const float* hs    = (const float*)d_in[0];
  const float* mask  = (const float*)d_in[1];
  const void*  pos   = d_in[2];
  const float* pastK = (const float*)d_in[3];
  const float* pastV = (const float*)d_in[4];
  const float* Wq    = (const float*)d_in[5];
  const float* Wk    = (const float*)d_in[6];
  const float* Wv    = (const float*)d_in[7];
  const float* Wo    = (const float*)d_in[8];

  float* out  = (float*)d_out;
  float* attn = out;                                        // 16*4096
  float* kc   = out + (size_t)NB * DMODEL;                  // 16*8*4096*128
  float* vc   = kc + (size_t)NB * NKV * SEQ * HD;

  float* ws      = (float*)d_ws;
  float* ws_q    = ws;                                         // 65536
  float* ws_raw  = ws_q + (size_t)NB * NH * HD;                // 16*6144
  float* ws_part = ws_raw + (size_t)NB * EQKV;                 // 16*32*16*136
  float* ws_ctx  = ws_part + (size_t)NB * NH * NCHUNK * PSTRIDE; // 65536

  qkv_proj<<<EQKV / 8, 256, 0, stream>>>(hs, Wq, Wk, Wv, ws_raw);
  rope_scatter<<<dim3(48, NB), 128, 0, stream>>>(ws_raw, pos, ws_q, kc, vc);
  attn_decode<<<dim3(NCHUNK, NKV, NB), 256, 0, stream>>>(pastK, pastV, ws_q, mask,
                                                         kc, vc, ws_part);
  combine<<<NB * NH, 64, 0, stream>>>(ws_part, ws_ctx);
  out_proj<<<DMODEL / 8, 256, 0, stream>>>(ws_ctx, Wo, attn);
}